// Round 4
// baseline (2806.814 us; speedup 1.0000x reference)
//
#include <hip/hip_runtime.h>

#define S_ 2048
#define E_ 1024
#define H_ 16
#define D_ 64
#define HB_ 204
#define RB_ 204
#define CB_ 408
#define NSCAN_ (S_ - CB_)
#define PEN_ 0.99f
#define NEGINF (-__builtin_huge_valf())
#define POSINF (__builtin_huge_valf())

typedef unsigned short u16;
typedef unsigned int u32;

__device__ __forceinline__ float bf2f(u16 u) {
    union { u32 u; float f; } a; a.u = ((u32)u) << 16; return a.f;
}
__device__ __forceinline__ u16 f2bf(float f) {
    union { float f; u32 u; } a; a.f = f;
    u32 r = (a.u + 0x7FFFu + ((a.u >> 16) & 1u)) >> 16;
    return (u16)r;
}

// ---------------------------------------------------------------------------
// Wave64 reductions via DPP. wsum64: result broadcast. wmind64: min in lane63.
// ---------------------------------------------------------------------------
#define DPPF(ID, V, CTRL, RMASK) \
    __int_as_float(__builtin_amdgcn_update_dpp(__float_as_int(ID), __float_as_int(V), CTRL, RMASK, 0xf, false))

__device__ __forceinline__ float wsum64(float v) {
    float t;
    t = DPPF(0.f, v, 0x111, 0xf); v += t;
    t = DPPF(0.f, v, 0x112, 0xf); v += t;
    t = DPPF(0.f, v, 0x114, 0xf); v += t;
    t = DPPF(0.f, v, 0x118, 0xf); v += t;
    t = DPPF(0.f, v, 0x142, 0xa); v += t;
    t = DPPF(0.f, v, 0x143, 0xc); v += t;
    return __int_as_float(__builtin_amdgcn_readlane(__float_as_int(v), 63));
}
// f64 min reduction: key doubles are positive/finite; identity = +inf double.
template <int CTRL, int RMASK>
__device__ __forceinline__ double dmin_step(double v) {
    const int lo = __double2loint(v), hi = __double2hiint(v);
    const int slo = __builtin_amdgcn_update_dpp(0, lo, CTRL, RMASK, 0xf, false);
    const int shi = __builtin_amdgcn_update_dpp(0x7FF00000, hi, CTRL, RMASK, 0xf, false);
    return fmin(v, __hiloint2double(shi, slo));
}
__device__ __forceinline__ double wmind64(double v) {
    v = dmin_step<0x111, 0xf>(v);
    v = dmin_step<0x112, 0xf>(v);
    v = dmin_step<0x114, 0xf>(v);
    v = dmin_step<0x118, 0xf>(v);
    v = dmin_step<0x142, 0xa>(v);   // row_bcast15
    v = dmin_step<0x143, 0xc>(v);   // row_bcast31
    return v;                        // lane 63 holds the wave min
}

// ---------------------------------------------------------------------------
// QKV projection: X[S,E] @ W^T + b -> head-major [H][S][D] f32.
// 128x128 tile, 8x8/thread, k-major LDS (ds_read_b128): VALU-bound 64 FMA : 4 b128.
// ---------------------------------------------------------------------------
__global__ __launch_bounds__(256) void qkv_gemm(
    const float* __restrict__ X,
    const float* __restrict__ W0, const float* __restrict__ b0,
    const float* __restrict__ W1, const float* __restrict__ b1,
    const float* __restrict__ W2, const float* __restrict__ b2,
    float* __restrict__ Q, float* __restrict__ K, float* __restrict__ V)
{
    const int z = blockIdx.z;
    const float* W    = (z == 0) ? W0 : (z == 1) ? W1 : W2;
    const float* bias = (z == 0) ? b0 : (z == 1) ? b1 : b2;
    float* dst        = (z == 0) ? Q  : (z == 1) ? K  : V;
    const int o0 = blockIdx.x * 128, s0 = blockIdx.y * 128;
    __shared__ float As[16][132];   // [k][m]
    __shared__ float Bs[16][132];   // [k][n]
    const int tid = threadIdx.x;
    const int ty = tid >> 4, tx = tid & 15;
    const int r = tid >> 1, kq = (tid & 1) << 3;   // row, k-quad base {0,8}
    float acc[8][8] = {};
    for (int kb = 0; kb < E_; kb += 16) {
        float4 a0 = *(const float4*)&X[(size_t)(s0 + r) * E_ + kb + kq];
        float4 a1 = *(const float4*)&X[(size_t)(s0 + r) * E_ + kb + kq + 4];
        float4 w0 = *(const float4*)&W[(size_t)(o0 + r) * E_ + kb + kq];
        float4 w1 = *(const float4*)&W[(size_t)(o0 + r) * E_ + kb + kq + 4];
        __syncthreads();
        As[kq+0][r]=a0.x; As[kq+1][r]=a0.y; As[kq+2][r]=a0.z; As[kq+3][r]=a0.w;
        As[kq+4][r]=a1.x; As[kq+5][r]=a1.y; As[kq+6][r]=a1.z; As[kq+7][r]=a1.w;
        Bs[kq+0][r]=w0.x; Bs[kq+1][r]=w0.y; Bs[kq+2][r]=w0.z; Bs[kq+3][r]=w0.w;
        Bs[kq+4][r]=w1.x; Bs[kq+5][r]=w1.y; Bs[kq+6][r]=w1.z; Bs[kq+7][r]=w1.w;
        __syncthreads();
        #pragma unroll
        for (int kk = 0; kk < 16; ++kk) {
            float av[8], bv[8];
            *(float4*)&av[0] = *(const float4*)&As[kk][ty * 8];
            *(float4*)&av[4] = *(const float4*)&As[kk][ty * 8 + 4];
            *(float4*)&bv[0] = *(const float4*)&Bs[kk][tx * 8];
            *(float4*)&bv[4] = *(const float4*)&Bs[kk][tx * 8 + 4];
            #pragma unroll
            for (int i = 0; i < 8; ++i)
                #pragma unroll
                for (int j = 0; j < 8; ++j) acc[i][j] += av[i] * bv[j];
        }
    }
    #pragma unroll
    for (int i = 0; i < 8; ++i) {
        const int s = s0 + ty * 8 + i;
        #pragma unroll
        for (int jq = 0; jq < 2; ++jq) {
            const int o = o0 + tx * 8 + jq * 4;
            float4 v;
            v.x = acc[i][jq*4+0] + bias[o+0];
            v.y = acc[i][jq*4+1] + bias[o+1];
            v.z = acc[i][jq*4+2] + bias[o+2];
            v.w = acc[i][jq*4+3] + bias[o+3];
            if (z == 0) { v.x *= 0.125f; v.y *= 0.125f; v.z *= 0.125f; v.w *= 0.125f; }
            *(float4*)&dst[((size_t)(o >> 6) * S_ + s) * D_ + (o & 63)] = v;
        }
    }
}

// ---------------------------------------------------------------------------
// Output projection: Y[S,E] = X[S,E] @ Wo^T + bo (same 128x128 structure)
// ---------------------------------------------------------------------------
__global__ __launch_bounds__(256) void proj_gemm(
    const float* __restrict__ X, const float* __restrict__ W,
    const float* __restrict__ bias, float* __restrict__ Y)
{
    const int o0 = blockIdx.x * 128, s0 = blockIdx.y * 128;
    __shared__ float As[16][132];
    __shared__ float Bs[16][132];
    const int tid = threadIdx.x;
    const int ty = tid >> 4, tx = tid & 15;
    const int r = tid >> 1, kq = (tid & 1) << 3;
    float acc[8][8] = {};
    for (int kb = 0; kb < E_; kb += 16) {
        float4 a0 = *(const float4*)&X[(size_t)(s0 + r) * E_ + kb + kq];
        float4 a1 = *(const float4*)&X[(size_t)(s0 + r) * E_ + kb + kq + 4];
        float4 w0 = *(const float4*)&W[(size_t)(o0 + r) * E_ + kb + kq];
        float4 w1 = *(const float4*)&W[(size_t)(o0 + r) * E_ + kb + kq + 4];
        __syncthreads();
        As[kq+0][r]=a0.x; As[kq+1][r]=a0.y; As[kq+2][r]=a0.z; As[kq+3][r]=a0.w;
        As[kq+4][r]=a1.x; As[kq+5][r]=a1.y; As[kq+6][r]=a1.z; As[kq+7][r]=a1.w;
        Bs[kq+0][r]=w0.x; Bs[kq+1][r]=w0.y; Bs[kq+2][r]=w0.z; Bs[kq+3][r]=w0.w;
        Bs[kq+4][r]=w1.x; Bs[kq+5][r]=w1.y; Bs[kq+6][r]=w1.z; Bs[kq+7][r]=w1.w;
        __syncthreads();
        #pragma unroll
        for (int kk = 0; kk < 16; ++kk) {
            float av[8], bv[8];
            *(float4*)&av[0] = *(const float4*)&As[kk][ty * 8];
            *(float4*)&av[4] = *(const float4*)&As[kk][ty * 8 + 4];
            *(float4*)&bv[0] = *(const float4*)&Bs[kk][tx * 8];
            *(float4*)&bv[4] = *(const float4*)&Bs[kk][tx * 8 + 4];
            #pragma unroll
            for (int i = 0; i < 8; ++i)
                #pragma unroll
                for (int j = 0; j < 8; ++j) acc[i][j] += av[i] * bv[j];
        }
    }
    #pragma unroll
    for (int i = 0; i < 8; ++i) {
        const int s = s0 + ty * 8 + i;
        #pragma unroll
        for (int jq = 0; jq < 2; ++jq) {
            const int o = o0 + tx * 8 + jq * 4;
            float4 v;
            v.x = acc[i][jq*4+0] + bias[o+0];
            v.y = acc[i][jq*4+1] + bias[o+1];
            v.z = acc[i][jq*4+2] + bias[o+2];
            v.w = acc[i][jq*4+3] + bias[o+3];
            *(float4*)&Y[(size_t)s * E_ + o] = v;
        }
    }
}

// ---------------------------------------------------------------------------
// Sc[h][i][j] = Q[h][i] . K[h][j]  (bf16 store). Only lower-tri tiles.
// ---------------------------------------------------------------------------
__global__ __launch_bounds__(256) void sc_gemm(const float* __restrict__ Q,
                                               const float* __restrict__ K,
                                               u16* __restrict__ Sc)
{
    const int h = blockIdx.z;
    const int jt = blockIdx.x, it = blockIdx.y;
    if (jt > it) return;
    const int i0 = it * 64, j0 = jt * 64;
    __shared__ float Qs[64][65];
    __shared__ float Ks[64][65];
    const float* Qh = Q + (size_t)h * S_ * D_;
    const float* Kh = K + (size_t)h * S_ * D_;
    const int tid = threadIdx.x;
    for (int idx = tid; idx < 1024; idx += 256) {
        const int rr = idx >> 4, c4 = (idx & 15) << 2;
        float4 q4 = *(const float4*)&Qh[(size_t)(i0 + rr) * D_ + c4];
        Qs[rr][c4] = q4.x; Qs[rr][c4 + 1] = q4.y; Qs[rr][c4 + 2] = q4.z; Qs[rr][c4 + 3] = q4.w;
        float4 k4 = *(const float4*)&Kh[(size_t)(j0 + rr) * D_ + c4];
        Ks[rr][c4] = k4.x; Ks[rr][c4 + 1] = k4.y; Ks[rr][c4 + 2] = k4.z; Ks[rr][c4 + 3] = k4.w;
    }
    __syncthreads();
    const int ty = tid >> 4, tx = tid & 15;
    float acc[4][4] = {};
    for (int kk = 0; kk < 64; ++kk) {
        float av[4], bv[4];
        #pragma unroll
        for (int i = 0; i < 4; ++i) av[i] = Qs[ty * 4 + i][kk];
        #pragma unroll
        for (int j = 0; j < 4; ++j) bv[j] = Ks[tx * 4 + j][kk];
        #pragma unroll
        for (int i = 0; i < 4; ++i)
            #pragma unroll
            for (int j = 0; j < 4; ++j) acc[i][j] += av[i] * bv[j];
    }
    u16* out = Sc + ((size_t)h * S_ + i0) * S_ + j0;
    #pragma unroll
    for (int i = 0; i < 4; ++i)
        #pragma unroll
        for (int j = 0; j < 4; ++j)
            out[(size_t)(ty * 4 + i) * S_ + tx * 4 + j] = f2bf(acc[i][j]);
}

// ---------------------------------------------------------------------------
// prep_kernel: rsum per scan row + acc-init over rows 0..407 (global atomics).
// ---------------------------------------------------------------------------
__global__ __launch_bounds__(256) void prep_kernel(const u16* __restrict__ Sc,
                                                   float* __restrict__ rsumG,
                                                   float* __restrict__ accG)
{
    const int h = blockIdx.y;
    const int wave = threadIdx.x >> 6, lane = threadIdx.x & 63;
    const int bx = blockIdx.x;
    if (bx < NSCAN_ / 4) {
        const int tok = CB_ + bx * 4 + wave;
        const u16* row = Sc + ((size_t)h * S_ + tok) * S_ + (tok - RB_);
        float sm = 0.f;
        #pragma unroll
        for (int k = 0; k < 4; ++k) {
            const int j = k * 64 + lane;
            if (j <= RB_) sm += __expf(bf2f(row[j]));
        }
        const float z = wsum64(sm);
        if (lane == 0) rsumG[(size_t)h * NSCAN_ + tok - CB_] = z;
    } else {
        const int t = (bx - NSCAN_ / 4) * 4 + wave;   // 0..407
        const u16* row = Sc + ((size_t)h * S_ + t) * S_;
        float sm = 0.f;
        for (int c = lane; c <= t; c += 64) sm += __expf(bf2f(row[c]));
        const float z = wsum64(sm);
        const float w = __powf(PEN_, (float)(CB_ - 1 - t)) / z;
        for (int c = lane; c <= t; c += 64)
            atomicAdd(&accG[h * CB_ + c], __expf(bf2f(row[c])) * w);
    }
}

// ---------------------------------------------------------------------------
// H2O serial scan, one wave/head. Restructured chain:
//  - gather+exp of 204 old heavy cols + candidate (slot 255 = lane63/k3) at
//    iter start, presumAll reduction overlaps the decision reduction
//  - single f64 DPP min: key = (acc_bits, ((2047-col)<<8)|slot) -> drop col,
//    tie -> larger col; slot payload gives exp(dropped) via one readlane
//  - Z = presumAll - exp(dropped) + rsum (exact: new set = old - bc + cand)
// ---------------------------------------------------------------------------
__global__ __launch_bounds__(64, 1) void scan_kernel(const u16* __restrict__ Sc,
                                                     const float* __restrict__ accG,
                                                     const float* __restrict__ rsumG,
                                                     u16* __restrict__ heavyOut)
{
    const int h = blockIdx.x;
    const int lane = threadIdx.x;
    __shared__ float ring[256];
    __shared__ float rsumLDS[NSCAN_];
    __shared__ __align__(16) u16 rowbuf[2][S_];
    const u16* sch = Sc + (size_t)h * S_ * S_;
    const float* accH = accG + h * CB_;
    u16* hOutH = heavyOut + (size_t)h * NSCAN_ * HB_;

    for (int i = lane; i < NSCAN_; i += 64) rsumLDS[i] = rsumG[(size_t)h * NSCAN_ + i];
    for (int i = lane; i < RB_; i += 64) ring[(HB_ + i) & 255] = accH[HB_ + i];

    // heavy slots j=k*64+lane (valid j<204). lane63/k3 = slot 255 = candidate.
    const int slotc[4] = {lane, 64 + lane, 128 + lane, 192 + lane};
    int hcol[4]; float hacc[4];
    #pragma unroll
    for (int k = 0; k < 4; ++k) {
        const bool v = (slotc[k] < HB_);
        hcol[k] = v ? slotc[k] : 0;
        hacc[k] = v ? accH[slotc[k]] : POSINF;
    }

    uint4 p0[4], p1[4], p2[4], p3[4];
    {
        const uint4* g = (const uint4*)(sch + (size_t)CB_ * S_);
        uint4* db = (uint4*)rowbuf[0];
        #pragma unroll
        for (int j = 0; j < 4; ++j) db[j * 64 + lane] = g[j * 64 + lane];
        const uint4* g0 = (const uint4*)(sch + (size_t)(CB_ + 1) * S_);
        const uint4* g1 = (const uint4*)(sch + (size_t)(CB_ + 2) * S_);
        const uint4* g2 = (const uint4*)(sch + (size_t)(CB_ + 3) * S_);
        const uint4* g3 = (const uint4*)(sch + (size_t)(CB_ + 4) * S_);
        #pragma unroll
        for (int j = 0; j < 4; ++j) { p0[j] = g0[j * 64 + lane]; p1[j] = g1[j * 64 + lane];
                                      p2[j] = g2[j * 64 + lane]; p3[j] = g3[j * 64 + lane]; }
    }

    float acc_cand;
    {   // ---- peeled tok = 408: heavy = {0..203}, nothing dropped ----
        const u16* srow = rowbuf[0];
        float e[4]; float lsum = 0.f;
        #pragma unroll
        for (int k = 0; k < 4; ++k) {
            const bool v = (slotc[k] < HB_);
            e[k] = v ? __expf(bf2f(srow[hcol[k]])) : 0.f;
            lsum += e[k];
        }
        const float Z = wsum64(lsum) + rsumLDS[0];
        const float invZ = __fdividef(1.f, Z);
        #pragma unroll
        for (int k = 0; k < 4; ++k) hacc[k] = hacc[k] * PEN_ + e[k] * invZ;
        #pragma unroll
        for (int k = 0; k < 4; ++k)
            if (slotc[k] < HB_) hOutH[slotc[k]] = (u16)slotc[k];
        float nv0 = 0.f;
        #pragma unroll
        for (int k = 0; k < 4; ++k) {
            if (slotc[k] <= RB_) {
                const int col = HB_ + slotc[k];          // li = 204
                const float p = __expf(bf2f(srow[col])) * invZ;
                const float old = (col == CB_) ? 0.f : ring[col & 255];
                const float nv = old * PEN_ + p;
                ring[col & 255] = nv;
                if (k == 0) nv0 = nv;
            }
        }
        acc_cand = __int_as_float(__builtin_amdgcn_readlane(__float_as_int(nv0), 0));
        uint4* db = (uint4*)rowbuf[1];
        #pragma unroll
        for (int j = 0; j < 4; ++j) db[j * 64 + lane] = p0[j];
    }

    auto iter = [&](int tok, uint4 (&pin)[4], uint4 (&pst)[4]) {
        const int li = tok - RB_;
        // insert candidate (col li-1, acc acc_cand) at slot 255
        if (lane == 63) { hcol[3] = li - 1; hacc[3] = acc_cand; }
        // prefetch row tok+4
        const int nr = (tok + 4 < S_) ? tok + 4 : S_ - 1;
        const uint4* gn = (const uint4*)(sch + (size_t)nr * S_);
        #pragma unroll
        for (int j = 0; j < 4; ++j) pin[j] = gn[j * 64 + lane];
        const float rsum = rsumLDS[tok - CB_];
        const u16* srow = rowbuf[tok & 1];

        // gather heavy+candidate scores, exp (independent of drop decision)
        const bool v3 = (lane < HB_ - 192) || (lane == 63);
        float e[4]; float lsum = 0.f;
        #pragma unroll
        for (int k = 0; k < 4; ++k) {
            const bool v = (k < 3) || v3;
            const float s = bf2f(srow[hcol[k]]);
            e[k] = v ? __expf(s) : 0.f;
            lsum += e[k];
        }
        // recent-window exps + ring reads (off-chain)
        float pw[4], oldw[4];
        #pragma unroll
        for (int k = 0; k < 4; ++k) {
            if (slotc[k] <= RB_) {
                const int col = li + slotc[k];
                pw[k] = __expf(bf2f(srow[col]));
                oldw[k] = (col == tok) ? 0.f : ring[col & 255];
            } else { pw[k] = 0.f; oldw[k] = 0.f; }
        }
        // single f64 argmin reduction
        double key = __hiloint2double(0x7F800000, 0x7FFFFFFF);
        #pragma unroll
        for (int k = 0; k < 4; ++k) {
            const int lo = ((2047 - hcol[k]) << 8) | slotc[k];
            key = fmin(key, __hiloint2double(__float_as_int(hacc[k]), lo));
        }
        key = wmind64(key);
        const float presum = wsum64(lsum);
        const int lo63 = __builtin_amdgcn_readlane(__double2loint(key), 63);
        const int slot = lo63 & 255;
        const int kb = slot >> 6, lb = slot & 63;
        const float esel = (kb == 0) ? e[0] : (kb == 1) ? e[1] : (kb == 2) ? e[2] : e[3];
        const float exp_bc = __int_as_float(__builtin_amdgcn_readlane(__float_as_int(esel), lb));
        const float exp_li1 = __int_as_float(__builtin_amdgcn_readlane(__float_as_int(e[3]), 63));
        const float Z = presum - exp_bc + rsum;
        const float invZ = __fdividef(1.f, Z);
        // replace dropped slot with candidate; update all heavy accs
        #pragma unroll
        for (int k = 0; k < 4; ++k) {
            const bool m = (slotc[k] == slot);
            const float base = m ? acc_cand : hacc[k];
            const float ee = m ? exp_li1 : e[k];
            hcol[k] = m ? (li - 1) : hcol[k];
            hacc[k] = base * PEN_ + ee * invZ;
        }
        // persist heavy set
        u16* hrow = hOutH + (size_t)(tok - CB_) * HB_;
        #pragma unroll
        for (int k = 0; k < 4; ++k)
            if (slotc[k] < HB_) hrow[slotc[k]] = (u16)hcol[k];
        // recent-window acc updates
        float nv0 = 0.f;
        #pragma unroll
        for (int k = 0; k < 4; ++k) {
            if (slotc[k] <= RB_) {
                const int col = li + slotc[k];
                const float nv = oldw[k] * PEN_ + pw[k] * invZ;
                ring[col & 255] = nv;
                if (k == 0) nv0 = nv;
            }
        }
        acc_cand = __int_as_float(__builtin_amdgcn_readlane(__float_as_int(nv0), 0));
        // stage row tok+1
        uint4* db = (uint4*)rowbuf[(tok + 1) & 1];
        #pragma unroll
        for (int j = 0; j < 4; ++j) db[j * 64 + lane] = pst[j];
    };

    for (int tok = CB_ + 1; tok + 3 < S_; tok += 4) {   // 409..2044
        iter(tok + 0, p0, p1);
        iter(tok + 1, p1, p2);
        iter(tok + 2, p2, p3);
        iter(tok + 3, p3, p0);
    }
    iter(S_ - 3, p0, p1);
    iter(S_ - 2, p1, p2);
    iter(S_ - 1, p2, p3);
}

// ---------------------------------------------------------------------------
// Final sparse attention: one block per (head,row).
// ---------------------------------------------------------------------------
__global__ __launch_bounds__(256) void attn_out(const u16* __restrict__ Sc,
                                                const float* __restrict__ V,
                                                const u16* __restrict__ heavyIn,
                                                float* __restrict__ O)
{
    const int bid = blockIdx.x;
    const int h = ((bid & 7) << 1) | ((bid >> 3) & 1);
    const int r = bid >> 4;
    const int tid = threadIdx.x;
    const int lane = tid & 63, wave = tid >> 6;
    __shared__ float sbuf[416];
    __shared__ u16 cbuf[416];
    __shared__ float wred[4];
    __shared__ float opart[4][64];
    const u16* srow = Sc + ((size_t)h * S_ + r) * S_;
    const int li = r - RB_;
    const int nact = (r < CB_) ? (r + 1) : (HB_ + RB_ + 1);
    const u16* hrow = (r < CB_) ? (const u16*)0
                                : heavyIn + ((size_t)h * NSCAN_ + (r - CB_)) * HB_;
    float lm = NEGINF;
    for (int i = tid; i < nact; i += 256) {
        int col;
        if (r < CB_) col = i;
        else col = (i < HB_) ? (int)hrow[i] : li + (i - HB_);
        const float s = bf2f(srow[col]);
        sbuf[i] = s; cbuf[i] = (u16)col;
        lm = fmaxf(lm, s);
    }
    #pragma unroll
    for (int o = 32; o > 0; o >>= 1) lm = fmaxf(lm, __shfl_xor(lm, o));
    if (lane == 0) wred[wave] = lm;
    __syncthreads();
    const float mx = fmaxf(fmaxf(wred[0], wred[1]), fmaxf(wred[2], wred[3]));
    __syncthreads();
    float ls = 0.f;
    for (int i = tid; i < nact; i += 256) {
        const float p = __expf(sbuf[i] - mx);
        sbuf[i] = p;
        ls += p;
    }
    #pragma unroll
    for (int o = 32; o > 0; o >>= 1) ls += __shfl_xor(ls, o);
    if (lane == 0) wred[wave] = ls;
    __syncthreads();
    const float Z = wred[0] + wred[1] + wred[2] + wred[3];
    float oacc = 0.f;
    const float* vh = V + (size_t)h * S_ * D_;
    for (int i = wave; i < nact; i += 4)
        oacc += sbuf[i] * vh[(size_t)cbuf[i] * D_ + lane];
    opart[wave][lane] = oacc;
    __syncthreads();
    if (tid < 64) {
        const float tot = (opart[0][tid] + opart[1][tid] + opart[2][tid] + opart[3][tid]) / Z;
        O[(size_t)r * E_ + h * D_ + tid] = tot;
    }
}

// ---------------------------------------------------------------------------
extern "C" void kernel_launch(void* const* d_in, const int* in_sizes, int n_in,
                              void* d_out, int out_size, void* d_ws, size_t ws_size,
                              hipStream_t stream)
{
    const float* hs = (const float*)d_in[0];
    const float* Wq = (const float*)d_in[2];
    const float* bq = (const float*)d_in[3];
    const float* Wk = (const float*)d_in[4];
    const float* bk = (const float*)d_in[5];
    const float* Wv = (const float*)d_in[6];
    const float* bv = (const float*)d_in[7];
    const float* Wo = (const float*)d_in[8];
    const float* bo = (const float*)d_in[9];

    char* ws = (char*)d_ws;
    const size_t MB = 1024 * 1024;
    float* Q     = (float*)(ws);                   //   8 MB [H][S][D]
    float* K     = (float*)(ws + 8 * MB);          //   8 MB
    float* V     = (float*)(ws + 16 * MB);         //   8 MB
    u16*   Sc    = (u16*)  (ws + 24 * MB);         // 128 MB [H][S][S] bf16
    u16*   hvy   = (u16*)  (ws + 152 * MB);        // ~10.2 MB [H][NSCAN][HB]
    float* rsumG = (float*)(ws + 163 * MB);        // 105 KB [H][NSCAN]
    float* accG  = (float*)(ws + 164 * MB);        //  26 KB [H][CB]
    float* O     = (float*)(ws + 168 * MB);        //   8 MB [S][E]
    (void)ws_size; (void)in_sizes; (void)n_in; (void)out_size;

    (void)hipMemsetAsync(accG, 0, (size_t)H_ * CB_ * sizeof(float), stream);
    qkv_gemm<<<dim3(8, 16, 3), 256, 0, stream>>>(hs, Wq, bq, Wk, bk, Wv, bv, Q, K, V);
    sc_gemm <<<dim3(32, 32, 16), 256, 0, stream>>>(Q, K, Sc);
    prep_kernel<<<dim3(NSCAN_ / 4 + CB_ / 4, H_), 256, 0, stream>>>(Sc, rsumG, accG);
    scan_kernel<<<16, 64, 0, stream>>>(Sc, accG, rsumG, hvy);
    attn_out<<<32768, 256, 0, stream>>>(Sc, V, hvy, O);
    proj_gemm<<<dim3(8, 16, 1), 256, 0, stream>>>(O, Wo, bo, (float*)d_out);
}

// Round 5
// 2261.073 us; speedup vs baseline: 1.2414x; 1.2414x over previous
//
#include <hip/hip_runtime.h>

#define S_ 2048
#define E_ 1024
#define H_ 16
#define D_ 64
#define HB_ 204
#define RB_ 204
#define CB_ 408
#define NSCAN_ (S_ - CB_)
#define PEN_ 0.99f
#define NEGINF (-__builtin_huge_valf())
#define POSINF (__builtin_huge_valf())

typedef unsigned short u16;
typedef unsigned int u32;
typedef unsigned int u32x4 __attribute__((ext_vector_type(4)));

__device__ __forceinline__ float bf2f(u16 u) {
    union { u32 u; float f; } a; a.u = ((u32)u) << 16; return a.f;
}
__device__ __forceinline__ u16 f2bf(float f) {
    union { float f; u32 u; } a; a.f = f;
    u32 r = (a.u + 0x7FFFu + ((a.u >> 16) & 1u)) >> 16;
    return (u16)r;
}

// ---------------------------------------------------------------------------
// Wave64 reductions via DPP. wsum64: result broadcast. wmind64: min in lane63.
// ---------------------------------------------------------------------------
#define DPPF(ID, V, CTRL, RMASK) \
    __int_as_float(__builtin_amdgcn_update_dpp(__float_as_int(ID), __float_as_int(V), CTRL, RMASK, 0xf, false))

__device__ __forceinline__ float wsum64(float v) {
    float t;
    t = DPPF(0.f, v, 0x111, 0xf); v += t;
    t = DPPF(0.f, v, 0x112, 0xf); v += t;
    t = DPPF(0.f, v, 0x114, 0xf); v += t;
    t = DPPF(0.f, v, 0x118, 0xf); v += t;
    t = DPPF(0.f, v, 0x142, 0xa); v += t;
    t = DPPF(0.f, v, 0x143, 0xc); v += t;
    return __int_as_float(__builtin_amdgcn_readlane(__float_as_int(v), 63));
}
// f64 min reduction: key doubles are positive/finite; identity = +inf double.
template <int CTRL, int RMASK>
__device__ __forceinline__ double dmin_step(double v) {
    const int lo = __double2loint(v), hi = __double2hiint(v);
    const int slo = __builtin_amdgcn_update_dpp(0, lo, CTRL, RMASK, 0xf, false);
    const int shi = __builtin_amdgcn_update_dpp(0x7FF00000, hi, CTRL, RMASK, 0xf, false);
    return fmin(v, __hiloint2double(shi, slo));
}
__device__ __forceinline__ double wmind64(double v) {
    v = dmin_step<0x111, 0xf>(v);
    v = dmin_step<0x112, 0xf>(v);
    v = dmin_step<0x114, 0xf>(v);
    v = dmin_step<0x118, 0xf>(v);
    v = dmin_step<0x142, 0xa>(v);   // row_bcast15
    v = dmin_step<0x143, 0xc>(v);   // row_bcast31
    return v;                        // lane 63 holds the wave min
}

// ---------------------------------------------------------------------------
// QKV projection: X[S,E] @ W^T + b -> head-major [H][S][D] f32.
// ---------------------------------------------------------------------------
__global__ __launch_bounds__(256) void qkv_gemm(
    const float* __restrict__ X,
    const float* __restrict__ W0, const float* __restrict__ b0,
    const float* __restrict__ W1, const float* __restrict__ b1,
    const float* __restrict__ W2, const float* __restrict__ b2,
    float* __restrict__ Q, float* __restrict__ K, float* __restrict__ V)
{
    const int z = blockIdx.z;
    const float* W    = (z == 0) ? W0 : (z == 1) ? W1 : W2;
    const float* bias = (z == 0) ? b0 : (z == 1) ? b1 : b2;
    float* dst        = (z == 0) ? Q  : (z == 1) ? K  : V;
    const int o0 = blockIdx.x * 128, s0 = blockIdx.y * 128;
    __shared__ float As[16][132];   // [k][m]
    __shared__ float Bs[16][132];   // [k][n]
    const int tid = threadIdx.x;
    const int ty = tid >> 4, tx = tid & 15;
    const int r = tid >> 1, kq = (tid & 1) << 3;   // row, k-quad base {0,8}
    float acc[8][8] = {};
    for (int kb = 0; kb < E_; kb += 16) {
        float4 a0 = *(const float4*)&X[(size_t)(s0 + r) * E_ + kb + kq];
        float4 a1 = *(const float4*)&X[(size_t)(s0 + r) * E_ + kb + kq + 4];
        float4 w0 = *(const float4*)&W[(size_t)(o0 + r) * E_ + kb + kq];
        float4 w1 = *(const float4*)&W[(size_t)(o0 + r) * E_ + kb + kq + 4];
        __syncthreads();
        As[kq+0][r]=a0.x; As[kq+1][r]=a0.y; As[kq+2][r]=a0.z; As[kq+3][r]=a0.w;
        As[kq+4][r]=a1.x; As[kq+5][r]=a1.y; As[kq+6][r]=a1.z; As[kq+7][r]=a1.w;
        Bs[kq+0][r]=w0.x; Bs[kq+1][r]=w0.y; Bs[kq+2][r]=w0.z; Bs[kq+3][r]=w0.w;
        Bs[kq+4][r]=w1.x; Bs[kq+5][r]=w1.y; Bs[kq+6][r]=w1.z; Bs[kq+7][r]=w1.w;
        __syncthreads();
        #pragma unroll
        for (int kk = 0; kk < 16; ++kk) {
            float av[8], bv[8];
            *(float4*)&av[0] = *(const float4*)&As[kk][ty * 8];
            *(float4*)&av[4] = *(const float4*)&As[kk][ty * 8 + 4];
            *(float4*)&bv[0] = *(const float4*)&Bs[kk][tx * 8];
            *(float4*)&bv[4] = *(const float4*)&Bs[kk][tx * 8 + 4];
            #pragma unroll
            for (int i = 0; i < 8; ++i)
                #pragma unroll
                for (int j = 0; j < 8; ++j) acc[i][j] += av[i] * bv[j];
        }
    }
    #pragma unroll
    for (int i = 0; i < 8; ++i) {
        const int s = s0 + ty * 8 + i;
        #pragma unroll
        for (int jq = 0; jq < 2; ++jq) {
            const int o = o0 + tx * 8 + jq * 4;
            float4 v;
            v.x = acc[i][jq*4+0] + bias[o+0];
            v.y = acc[i][jq*4+1] + bias[o+1];
            v.z = acc[i][jq*4+2] + bias[o+2];
            v.w = acc[i][jq*4+3] + bias[o+3];
            if (z == 0) { v.x *= 0.125f; v.y *= 0.125f; v.z *= 0.125f; v.w *= 0.125f; }
            *(float4*)&dst[((size_t)(o >> 6) * S_ + s) * D_ + (o & 63)] = v;
        }
    }
}

// ---------------------------------------------------------------------------
// Output projection: Y[S,E] = X[S,E] @ Wo^T + bo
// ---------------------------------------------------------------------------
__global__ __launch_bounds__(256) void proj_gemm(
    const float* __restrict__ X, const float* __restrict__ W,
    const float* __restrict__ bias, float* __restrict__ Y)
{
    const int o0 = blockIdx.x * 128, s0 = blockIdx.y * 128;
    __shared__ float As[16][132];
    __shared__ float Bs[16][132];
    const int tid = threadIdx.x;
    const int ty = tid >> 4, tx = tid & 15;
    const int r = tid >> 1, kq = (tid & 1) << 3;
    float acc[8][8] = {};
    for (int kb = 0; kb < E_; kb += 16) {
        float4 a0 = *(const float4*)&X[(size_t)(s0 + r) * E_ + kb + kq];
        float4 a1 = *(const float4*)&X[(size_t)(s0 + r) * E_ + kb + kq + 4];
        float4 w0 = *(const float4*)&W[(size_t)(o0 + r) * E_ + kb + kq];
        float4 w1 = *(const float4*)&W[(size_t)(o0 + r) * E_ + kb + kq + 4];
        __syncthreads();
        As[kq+0][r]=a0.x; As[kq+1][r]=a0.y; As[kq+2][r]=a0.z; As[kq+3][r]=a0.w;
        As[kq+4][r]=a1.x; As[kq+5][r]=a1.y; As[kq+6][r]=a1.z; As[kq+7][r]=a1.w;
        Bs[kq+0][r]=w0.x; Bs[kq+1][r]=w0.y; Bs[kq+2][r]=w0.z; Bs[kq+3][r]=w0.w;
        Bs[kq+4][r]=w1.x; Bs[kq+5][r]=w1.y; Bs[kq+6][r]=w1.z; Bs[kq+7][r]=w1.w;
        __syncthreads();
        #pragma unroll
        for (int kk = 0; kk < 16; ++kk) {
            float av[8], bv[8];
            *(float4*)&av[0] = *(const float4*)&As[kk][ty * 8];
            *(float4*)&av[4] = *(const float4*)&As[kk][ty * 8 + 4];
            *(float4*)&bv[0] = *(const float4*)&Bs[kk][tx * 8];
            *(float4*)&bv[4] = *(const float4*)&Bs[kk][tx * 8 + 4];
            #pragma unroll
            for (int i = 0; i < 8; ++i)
                #pragma unroll
                for (int j = 0; j < 8; ++j) acc[i][j] += av[i] * bv[j];
        }
    }
    #pragma unroll
    for (int i = 0; i < 8; ++i) {
        const int s = s0 + ty * 8 + i;
        #pragma unroll
        for (int jq = 0; jq < 2; ++jq) {
            const int o = o0 + tx * 8 + jq * 4;
            float4 v;
            v.x = acc[i][jq*4+0] + bias[o+0];
            v.y = acc[i][jq*4+1] + bias[o+1];
            v.z = acc[i][jq*4+2] + bias[o+2];
            v.w = acc[i][jq*4+3] + bias[o+3];
            *(float4*)&Y[(size_t)s * E_ + o] = v;
        }
    }
}

// ---------------------------------------------------------------------------
// Sc[h][i][j] = Q[h][i] . K[h][j]  (bf16 store). Only lower-tri tiles.
// ---------------------------------------------------------------------------
__global__ __launch_bounds__(256) void sc_gemm(const float* __restrict__ Q,
                                               const float* __restrict__ K,
                                               u16* __restrict__ Sc)
{
    const int h = blockIdx.z;
    const int jt = blockIdx.x, it = blockIdx.y;
    if (jt > it) return;
    const int i0 = it * 64, j0 = jt * 64;
    __shared__ float Qs[64][65];
    __shared__ float Ks[64][65];
    const float* Qh = Q + (size_t)h * S_ * D_;
    const float* Kh = K + (size_t)h * S_ * D_;
    const int tid = threadIdx.x;
    for (int idx = tid; idx < 1024; idx += 256) {
        const int rr = idx >> 4, c4 = (idx & 15) << 2;
        float4 q4 = *(const float4*)&Qh[(size_t)(i0 + rr) * D_ + c4];
        Qs[rr][c4] = q4.x; Qs[rr][c4 + 1] = q4.y; Qs[rr][c4 + 2] = q4.z; Qs[rr][c4 + 3] = q4.w;
        float4 k4 = *(const float4*)&Kh[(size_t)(j0 + rr) * D_ + c4];
        Ks[rr][c4] = k4.x; Ks[rr][c4 + 1] = k4.y; Ks[rr][c4 + 2] = k4.z; Ks[rr][c4 + 3] = k4.w;
    }
    __syncthreads();
    const int ty = tid >> 4, tx = tid & 15;
    float acc[4][4] = {};
    for (int kk = 0; kk < 64; ++kk) {
        float av[4], bv[4];
        #pragma unroll
        for (int i = 0; i < 4; ++i) av[i] = Qs[ty * 4 + i][kk];
        #pragma unroll
        for (int j = 0; j < 4; ++j) bv[j] = Ks[tx * 4 + j][kk];
        #pragma unroll
        for (int i = 0; i < 4; ++i)
            #pragma unroll
            for (int j = 0; j < 4; ++j) acc[i][j] += av[i] * bv[j];
    }
    u16* out = Sc + ((size_t)h * S_ + i0) * S_ + j0;
    #pragma unroll
    for (int i = 0; i < 4; ++i)
        #pragma unroll
        for (int j = 0; j < 4; ++j)
            out[(size_t)(ty * 4 + i) * S_ + tx * 4 + j] = f2bf(acc[i][j]);
}

// ---------------------------------------------------------------------------
// prep_kernel: rsum per scan row + acc-init over rows 0..407 (global atomics).
// ---------------------------------------------------------------------------
__global__ __launch_bounds__(256) void prep_kernel(const u16* __restrict__ Sc,
                                                   float* __restrict__ rsumG,
                                                   float* __restrict__ accG)
{
    const int h = blockIdx.y;
    const int wave = threadIdx.x >> 6, lane = threadIdx.x & 63;
    const int bx = blockIdx.x;
    if (bx < NSCAN_ / 4) {
        const int tok = CB_ + bx * 4 + wave;
        const u16* row = Sc + ((size_t)h * S_ + tok) * S_ + (tok - RB_);
        float sm = 0.f;
        #pragma unroll
        for (int k = 0; k < 4; ++k) {
            const int j = k * 64 + lane;
            if (j <= RB_) sm += __expf(bf2f(row[j]));
        }
        const float z = wsum64(sm);
        if (lane == 0) rsumG[(size_t)h * NSCAN_ + tok - CB_] = z;
    } else {
        const int t = (bx - NSCAN_ / 4) * 4 + wave;   // 0..407
        const u16* row = Sc + ((size_t)h * S_ + t) * S_;
        float sm = 0.f;
        for (int c = lane; c <= t; c += 64) sm += __expf(bf2f(row[c]));
        const float z = wsum64(sm);
        const float w = __powf(PEN_, (float)(CB_ - 1 - t)) / z;
        for (int c = lane; c <= t; c += 64)
            atomicAdd(&accG[h * CB_ + c], __expf(bf2f(row[c])) * w);
    }
}

// ---------------------------------------------------------------------------
// H2O serial scan, one wave/head. The score-row prefetch is hand-issued with
// asm volatile global_load_dwordx4 (4 rows / 64 VGPRs in flight) so the
// register allocator CANNOT demote it (round-4 post-mortem: VGPR=68 proved
// the compiler sank the C-level prefetch to its use, serializing on memory
// latency every iter). s_waitcnt vmcnt(12) before staging row tok+1: rows
// tok+2/3/4 (12 loads) are always newer, so vmcnt(12) is sufficient and
// keeps ~3 rows in flight (never vmcnt(0)).
// ---------------------------------------------------------------------------
__global__ __launch_bounds__(64, 1) void scan_kernel(const u16* __restrict__ Sc,
                                                     const float* __restrict__ accG,
                                                     const float* __restrict__ rsumG,
                                                     u16* __restrict__ heavyOut)
{
    const int h = blockIdx.x;
    const int lane = threadIdx.x;
    __shared__ float ring[256];
    __shared__ float rsumLDS[NSCAN_];
    __shared__ __align__(16) u16 rowbuf[2][S_];
    const u16* sch = Sc + (size_t)h * S_ * S_;
    const float* accH = accG + h * CB_;
    u16* hOutH = heavyOut + (size_t)h * NSCAN_ * HB_;

    for (int i = lane; i < NSCAN_; i += 64) rsumLDS[i] = rsumG[(size_t)h * NSCAN_ + i];
    for (int i = lane; i < RB_; i += 64) ring[(HB_ + i) & 255] = accH[HB_ + i];

    // heavy slots j=k*64+lane (valid j<204). lane63/k3 = slot 255 = candidate.
    const int slotc[4] = {lane, 64 + lane, 128 + lane, 192 + lane};
    int hcol[4]; float hacc[4];
    #pragma unroll
    for (int k = 0; k < 4; ++k) {
        const bool v = (slotc[k] < HB_);
        hcol[k] = v ? slotc[k] : 0;
        hacc[k] = v ? accH[slotc[k]] : POSINF;
    }

    // ---- asm prefetch machinery: buffer for row r is p[r&3] ----
    u32x4 p0[4], p1[4], p2[4], p3[4];
    #define ISSUE_ROW(BUF, ROWI)                                                 \
        do {                                                                     \
            const void* _ap = (const void*)((const char*)(sch + (size_t)(ROWI) * S_) + lane * 16); \
            asm volatile("global_load_dwordx4 %0, %4, off\n\t"                   \
                         "global_load_dwordx4 %1, %4, off offset:1024\n\t"       \
                         "global_load_dwordx4 %2, %4, off offset:2048\n\t"       \
                         "global_load_dwordx4 %3, %4, off offset:3072"           \
                         : "=v"(BUF[0]), "=v"(BUF[1]), "=v"(BUF[2]), "=v"(BUF[3]) \
                         : "v"(_ap) : "memory");                                 \
        } while (0)
    #define WAIT_VM12() asm volatile("s_waitcnt vmcnt(12)" ::: "memory")

    // prologue: rows CB..CB+3 in flight; stage row CB into rowbuf[0]
    ISSUE_ROW(p0, CB_ + 0);
    ISSUE_ROW(p1, CB_ + 1);
    ISSUE_ROW(p2, CB_ + 2);
    ISSUE_ROW(p3, CB_ + 3);
    WAIT_VM12();                       // 12 newer loads -> row CB done
    {
        u32x4* db = (u32x4*)rowbuf[0];
        #pragma unroll
        for (int j = 0; j < 4; ++j) db[j * 64 + lane] = p0[j];
    }

    float acc_cand;
    {   // ---- peeled tok = 408 (buf[408&3]=p0 freed -> row 412) ----
        ISSUE_ROW(p0, CB_ + 4);
        const u16* srow = rowbuf[0];
        float e[4]; float lsum = 0.f;
        #pragma unroll
        for (int k = 0; k < 4; ++k) {
            const bool v = (slotc[k] < HB_);
            e[k] = v ? __expf(bf2f(srow[hcol[k]])) : 0.f;
            lsum += e[k];
        }
        const float Z = wsum64(lsum) + rsumLDS[0];
        const float invZ = __fdividef(1.f, Z);
        #pragma unroll
        for (int k = 0; k < 4; ++k) hacc[k] = hacc[k] * PEN_ + e[k] * invZ;
        #pragma unroll
        for (int k = 0; k < 4; ++k)
            if (slotc[k] < HB_) hOutH[slotc[k]] = (u16)slotc[k];
        float nv0 = 0.f;
        #pragma unroll
        for (int k = 0; k < 4; ++k) {
            if (slotc[k] <= RB_) {
                const int col = HB_ + slotc[k];          // li = 204
                const float p = __expf(bf2f(srow[col])) * invZ;
                const float old = (col == CB_) ? 0.f : ring[col & 255];
                const float nv = old * PEN_ + p;
                ring[col & 255] = nv;
                if (k == 0) nv0 = nv;
            }
        }
        acc_cand = __int_as_float(__builtin_amdgcn_readlane(__float_as_int(nv0), 0));
        WAIT_VM12();                   // rows 410,411,412 newer -> row 409 done
        u32x4* db = (u32x4*)rowbuf[1];
        #pragma unroll
        for (int j = 0; j < 4; ++j) db[j * 64 + lane] = p1[j];
    }

    auto iter = [&](int tok, u32x4 (&ld)[4], u32x4 (&st)[4]) {
        const int li = tok - RB_;
        // refill the buffer freed last iter with row tok+4
        const int nr = (tok + 4 < S_) ? tok + 4 : S_ - 1;
        ISSUE_ROW(ld, nr);
        // insert candidate (col li-1, acc acc_cand) at slot 255
        if (lane == 63) { hcol[3] = li - 1; hacc[3] = acc_cand; }
        const float rsum = rsumLDS[tok - CB_];
        const u16* srow = rowbuf[tok & 1];

        // gather heavy+candidate scores, exp (independent of drop decision)
        const bool v3 = (lane < HB_ - 192) || (lane == 63);
        float e[4]; float lsum = 0.f;
        #pragma unroll
        for (int k = 0; k < 4; ++k) {
            const bool v = (k < 3) || v3;
            const float s = bf2f(srow[hcol[k]]);
            e[k] = v ? __expf(s) : 0.f;
            lsum += e[k];
        }
        // recent-window exps + ring reads (off-chain)
        float pw[4], oldw[4];
        #pragma unroll
        for (int k = 0; k < 4; ++k) {
            if (slotc[k] <= RB_) {
                const int col = li + slotc[k];
                pw[k] = __expf(bf2f(srow[col]));
                oldw[k] = (col == tok) ? 0.f : ring[col & 255];
            } else { pw[k] = 0.f; oldw[k] = 0.f; }
        }
        // single f64 argmin reduction
        double key = __hiloint2double(0x7F800000, 0x7FFFFFFF);
        #pragma unroll
        for (int k = 0; k < 4; ++k) {
            const int lo = ((2047 - hcol[k]) << 8) | slotc[k];
            key = fmin(key, __hiloint2double(__float_as_int(hacc[k]), lo));
        }
        key = wmind64(key);
        const float presum = wsum64(lsum);
        const int lo63 = __builtin_amdgcn_readlane(__double2loint(key), 63);
        const int slot = lo63 & 255;
        const int kb = slot >> 6, lb = slot & 63;
        const float esel = (kb == 0) ? e[0] : (kb == 1) ? e[1] : (kb == 2) ? e[2] : e[3];
        const float exp_bc = __int_as_float(__builtin_amdgcn_readlane(__float_as_int(esel), lb));
        const float exp_li1 = __int_as_float(__builtin_amdgcn_readlane(__float_as_int(e[3]), 63));
        const float Z = presum - exp_bc + rsum;
        const float invZ = __fdividef(1.f, Z);
        // replace dropped slot with candidate; update all heavy accs
        #pragma unroll
        for (int k = 0; k < 4; ++k) {
            const bool m = (slotc[k] == slot);
            const float base = m ? acc_cand : hacc[k];
            const float ee = m ? exp_li1 : e[k];
            hcol[k] = m ? (li - 1) : hcol[k];
            hacc[k] = base * PEN_ + ee * invZ;
        }
        // persist heavy set
        u16* hrow = hOutH + (size_t)(tok - CB_) * HB_;
        #pragma unroll
        for (int k = 0; k < 4; ++k)
            if (slotc[k] < HB_) hrow[slotc[k]] = (u16)hcol[k];
        // recent-window acc updates
        float nv0 = 0.f;
        #pragma unroll
        for (int k = 0; k < 4; ++k) {
            if (slotc[k] <= RB_) {
                const int col = li + slotc[k];
                const float nv = oldw[k] * PEN_ + pw[k] * invZ;
                ring[col & 255] = nv;
                if (k == 0) nv0 = nv;
            }
        }
        acc_cand = __int_as_float(__builtin_amdgcn_readlane(__float_as_int(nv0), 0));
        // stage row tok+1 (loads issued 3 iters ago; >=12 newer loads exist)
        WAIT_VM12();
        u32x4* db = (u32x4*)rowbuf[(tok + 1) & 1];
        #pragma unroll
        for (int j = 0; j < 4; ++j) db[j * 64 + lane] = st[j];
    };

    for (int tok = CB_ + 1; tok + 3 < S_; tok += 4) {   // 409..2044
        iter(tok + 0, p1, p2);
        iter(tok + 1, p2, p3);
        iter(tok + 2, p3, p0);
        iter(tok + 3, p0, p1);
    }
    iter(S_ - 3, p1, p2);
    iter(S_ - 2, p2, p3);
    iter(S_ - 1, p3, p0);
    #undef ISSUE_ROW
    #undef WAIT_VM12
}

// ---------------------------------------------------------------------------
// Final sparse attention: one block per (head,row).
// ---------------------------------------------------------------------------
__global__ __launch_bounds__(256) void attn_out(const u16* __restrict__ Sc,
                                                const float* __restrict__ V,
                                                const u16* __restrict__ heavyIn,
                                                float* __restrict__ O)
{
    const int bid = blockIdx.x;
    const int h = ((bid & 7) << 1) | ((bid >> 3) & 1);
    const int r = bid >> 4;
    const int tid = threadIdx.x;
    const int lane = tid & 63, wave = tid >> 6;
    __shared__ float sbuf[416];
    __shared__ u16 cbuf[416];
    __shared__ float wred[4];
    __shared__ float opart[4][64];
    const u16* srow = Sc + ((size_t)h * S_ + r) * S_;
    const int li = r - RB_;
    const int nact = (r < CB_) ? (r + 1) : (HB_ + RB_ + 1);
    const u16* hrow = (r < CB_) ? (const u16*)0
                                : heavyIn + ((size_t)h * NSCAN_ + (r - CB_)) * HB_;
    float lm = NEGINF;
    for (int i = tid; i < nact; i += 256) {
        int col;
        if (r < CB_) col = i;
        else col = (i < HB_) ? (int)hrow[i] : li + (i - HB_);
        const float s = bf2f(srow[col]);
        sbuf[i] = s; cbuf[i] = (u16)col;
        lm = fmaxf(lm, s);
    }
    #pragma unroll
    for (int o = 32; o > 0; o >>= 1) lm = fmaxf(lm, __shfl_xor(lm, o));
    if (lane == 0) wred[wave] = lm;
    __syncthreads();
    const float mx = fmaxf(fmaxf(wred[0], wred[1]), fmaxf(wred[2], wred[3]));
    __syncthreads();
    float ls = 0.f;
    for (int i = tid; i < nact; i += 256) {
        const float p = __expf(sbuf[i] - mx);
        sbuf[i] = p;
        ls += p;
    }
    #pragma unroll
    for (int o = 32; o > 0; o >>= 1) ls += __shfl_xor(ls, o);
    if (lane == 0) wred[wave] = ls;
    __syncthreads();
    const float Z = wred[0] + wred[1] + wred[2] + wred[3];
    float oacc = 0.f;
    const float* vh = V + (size_t)h * S_ * D_;
    for (int i = wave; i < nact; i += 4)
        oacc += sbuf[i] * vh[(size_t)cbuf[i] * D_ + lane];
    opart[wave][lane] = oacc;
    __syncthreads();
    if (tid < 64) {
        const float tot = (opart[0][tid] + opart[1][tid] + opart[2][tid] + opart[3][tid]) / Z;
        O[(size_t)r * E_ + h * D_ + tid] = tot;
    }
}

// ---------------------------------------------------------------------------
extern "C" void kernel_launch(void* const* d_in, const int* in_sizes, int n_in,
                              void* d_out, int out_size, void* d_ws, size_t ws_size,
                              hipStream_t stream)
{
    const float* hs = (const float*)d_in[0];
    const float* Wq = (const float*)d_in[2];
    const float* bq = (const float*)d_in[3];
    const float* Wk = (const float*)d_in[4];
    const float* bk = (const float*)d_in[5];
    const float* Wv = (const float*)d_in[6];
    const float* bv = (const float*)d_in[7];
    const float* Wo = (const float*)d_in[8];
    const float* bo = (const float*)d_in[9];

    char* ws = (char*)d_ws;
    const size_t MB = 1024 * 1024;
    float* Q     = (float*)(ws);                   //   8 MB [H][S][D]
    float* K     = (float*)(ws + 8 * MB);          //   8 MB
    float* V     = (float*)(ws + 16 * MB);         //   8 MB
    u16*   Sc    = (u16*)  (ws + 24 * MB);         // 128 MB [H][S][S] bf16
    u16*   hvy   = (u16*)  (ws + 152 * MB);        // ~10.2 MB [H][NSCAN][HB]
    float* rsumG = (float*)(ws + 163 * MB);        // 105 KB [H][NSCAN]
    float* accG  = (float*)(ws + 164 * MB);        //  26 KB [H][CB]
    float* O     = (float*)(ws + 168 * MB);        //   8 MB [S][E]
    (void)ws_size; (void)in_sizes; (void)n_in; (void)out_size;

    (void)hipMemsetAsync(accG, 0, (size_t)H_ * CB_ * sizeof(float), stream);
    qkv_gemm<<<dim3(8, 16, 3), 256, 0, stream>>>(hs, Wq, bq, Wk, bk, Wv, bv, Q, K, V);
    sc_gemm <<<dim3(32, 32, 16), 256, 0, stream>>>(Q, K, Sc);
    prep_kernel<<<dim3(NSCAN_ / 4 + CB_ / 4, H_), 256, 0, stream>>>(Sc, rsumG, accG);
    scan_kernel<<<16, 64, 0, stream>>>(Sc, accG, rsumG, hvy);
    attn_out<<<32768, 256, 0, stream>>>(Sc, V, hvy, O);
    proj_gemm<<<dim3(8, 16, 1), 256, 0, stream>>>(O, Wo, bo, (float*)d_out);
}

// Round 6
// 2241.916 us; speedup vs baseline: 1.2520x; 1.0085x over previous
//
#include <hip/hip_runtime.h>

#define S_ 2048
#define E_ 1024
#define H_ 16
#define D_ 64
#define HB_ 204
#define RB_ 204
#define CB_ 408
#define NSCAN_ (S_ - CB_)
#define PEN_ 0.99f
#define NEGINF (-__builtin_huge_valf())
#define POSINF (__builtin_huge_valf())

typedef unsigned short u16;
typedef unsigned int u32;
typedef unsigned int u32x4 __attribute__((ext_vector_type(4)));

__device__ __forceinline__ float bf2f(u16 u) {
    union { u32 u; float f; } a; a.u = ((u32)u) << 16; return a.f;
}
__device__ __forceinline__ u16 f2bf(float f) {
    union { float f; u32 u; } a; a.f = f;
    u32 r = (a.u + 0x7FFFu + ((a.u >> 16) & 1u)) >> 16;
    return (u16)r;
}

// ---------------------------------------------------------------------------
// Wave64 reductions via DPP. wsum64: result broadcast. wmind64: min in lane63.
// ---------------------------------------------------------------------------
#define DPPF(ID, V, CTRL, RMASK) \
    __int_as_float(__builtin_amdgcn_update_dpp(__float_as_int(ID), __float_as_int(V), CTRL, RMASK, 0xf, false))

__device__ __forceinline__ float wsum64(float v) {
    float t;
    t = DPPF(0.f, v, 0x111, 0xf); v += t;
    t = DPPF(0.f, v, 0x112, 0xf); v += t;
    t = DPPF(0.f, v, 0x114, 0xf); v += t;
    t = DPPF(0.f, v, 0x118, 0xf); v += t;
    t = DPPF(0.f, v, 0x142, 0xa); v += t;
    t = DPPF(0.f, v, 0x143, 0xc); v += t;
    return __int_as_float(__builtin_amdgcn_readlane(__float_as_int(v), 63));
}
// f64 min reduction: key doubles are positive/finite; identity = +inf double.
template <int CTRL, int RMASK>
__device__ __forceinline__ double dmin_step(double v) {
    const int lo = __double2loint(v), hi = __double2hiint(v);
    const int slo = __builtin_amdgcn_update_dpp(0, lo, CTRL, RMASK, 0xf, false);
    const int shi = __builtin_amdgcn_update_dpp(0x7FF00000, hi, CTRL, RMASK, 0xf, false);
    return fmin(v, __hiloint2double(shi, slo));
}
__device__ __forceinline__ double wmind64(double v) {
    v = dmin_step<0x111, 0xf>(v);
    v = dmin_step<0x112, 0xf>(v);
    v = dmin_step<0x114, 0xf>(v);
    v = dmin_step<0x118, 0xf>(v);
    v = dmin_step<0x142, 0xa>(v);   // row_bcast15
    v = dmin_step<0x143, 0xc>(v);   // row_bcast31
    return v;                        // lane 63 holds the wave min
}

// ---------------------------------------------------------------------------
// QKV projection: X[S,E] @ W^T + b -> head-major [H][S][D] f32.
// ---------------------------------------------------------------------------
__global__ __launch_bounds__(256) void qkv_gemm(
    const float* __restrict__ X,
    const float* __restrict__ W0, const float* __restrict__ b0,
    const float* __restrict__ W1, const float* __restrict__ b1,
    const float* __restrict__ W2, const float* __restrict__ b2,
    float* __restrict__ Q, float* __restrict__ K, float* __restrict__ V)
{
    const int z = blockIdx.z;
    const float* W    = (z == 0) ? W0 : (z == 1) ? W1 : W2;
    const float* bias = (z == 0) ? b0 : (z == 1) ? b1 : b2;
    float* dst        = (z == 0) ? Q  : (z == 1) ? K  : V;
    const int o0 = blockIdx.x * 128, s0 = blockIdx.y * 128;
    __shared__ float As[16][132];   // [k][m]
    __shared__ float Bs[16][132];   // [k][n]
    const int tid = threadIdx.x;
    const int ty = tid >> 4, tx = tid & 15;
    const int r = tid >> 1, kq = (tid & 1) << 3;   // row, k-quad base {0,8}
    float acc[8][8] = {};
    for (int kb = 0; kb < E_; kb += 16) {
        float4 a0 = *(const float4*)&X[(size_t)(s0 + r) * E_ + kb + kq];
        float4 a1 = *(const float4*)&X[(size_t)(s0 + r) * E_ + kb + kq + 4];
        float4 w0 = *(const float4*)&W[(size_t)(o0 + r) * E_ + kb + kq];
        float4 w1 = *(const float4*)&W[(size_t)(o0 + r) * E_ + kb + kq + 4];
        __syncthreads();
        As[kq+0][r]=a0.x; As[kq+1][r]=a0.y; As[kq+2][r]=a0.z; As[kq+3][r]=a0.w;
        As[kq+4][r]=a1.x; As[kq+5][r]=a1.y; As[kq+6][r]=a1.z; As[kq+7][r]=a1.w;
        Bs[kq+0][r]=w0.x; Bs[kq+1][r]=w0.y; Bs[kq+2][r]=w0.z; Bs[kq+3][r]=w0.w;
        Bs[kq+4][r]=w1.x; Bs[kq+5][r]=w1.y; Bs[kq+6][r]=w1.z; Bs[kq+7][r]=w1.w;
        __syncthreads();
        #pragma unroll
        for (int kk = 0; kk < 16; ++kk) {
            float av[8], bv[8];
            *(float4*)&av[0] = *(const float4*)&As[kk][ty * 8];
            *(float4*)&av[4] = *(const float4*)&As[kk][ty * 8 + 4];
            *(float4*)&bv[0] = *(const float4*)&Bs[kk][tx * 8];
            *(float4*)&bv[4] = *(const float4*)&Bs[kk][tx * 8 + 4];
            #pragma unroll
            for (int i = 0; i < 8; ++i)
                #pragma unroll
                for (int j = 0; j < 8; ++j) acc[i][j] += av[i] * bv[j];
        }
    }
    #pragma unroll
    for (int i = 0; i < 8; ++i) {
        const int s = s0 + ty * 8 + i;
        #pragma unroll
        for (int jq = 0; jq < 2; ++jq) {
            const int o = o0 + tx * 8 + jq * 4;
            float4 v;
            v.x = acc[i][jq*4+0] + bias[o+0];
            v.y = acc[i][jq*4+1] + bias[o+1];
            v.z = acc[i][jq*4+2] + bias[o+2];
            v.w = acc[i][jq*4+3] + bias[o+3];
            if (z == 0) { v.x *= 0.125f; v.y *= 0.125f; v.z *= 0.125f; v.w *= 0.125f; }
            *(float4*)&dst[((size_t)(o >> 6) * S_ + s) * D_ + (o & 63)] = v;
        }
    }
}

// ---------------------------------------------------------------------------
// Output projection: Y[S,E] = X[S,E] @ Wo^T + bo
// ---------------------------------------------------------------------------
__global__ __launch_bounds__(256) void proj_gemm(
    const float* __restrict__ X, const float* __restrict__ W,
    const float* __restrict__ bias, float* __restrict__ Y)
{
    const int o0 = blockIdx.x * 128, s0 = blockIdx.y * 128;
    __shared__ float As[16][132];
    __shared__ float Bs[16][132];
    const int tid = threadIdx.x;
    const int ty = tid >> 4, tx = tid & 15;
    const int r = tid >> 1, kq = (tid & 1) << 3;
    float acc[8][8] = {};
    for (int kb = 0; kb < E_; kb += 16) {
        float4 a0 = *(const float4*)&X[(size_t)(s0 + r) * E_ + kb + kq];
        float4 a1 = *(const float4*)&X[(size_t)(s0 + r) * E_ + kb + kq + 4];
        float4 w0 = *(const float4*)&W[(size_t)(o0 + r) * E_ + kb + kq];
        float4 w1 = *(const float4*)&W[(size_t)(o0 + r) * E_ + kb + kq + 4];
        __syncthreads();
        As[kq+0][r]=a0.x; As[kq+1][r]=a0.y; As[kq+2][r]=a0.z; As[kq+3][r]=a0.w;
        As[kq+4][r]=a1.x; As[kq+5][r]=a1.y; As[kq+6][r]=a1.z; As[kq+7][r]=a1.w;
        Bs[kq+0][r]=w0.x; Bs[kq+1][r]=w0.y; Bs[kq+2][r]=w0.z; Bs[kq+3][r]=w0.w;
        Bs[kq+4][r]=w1.x; Bs[kq+5][r]=w1.y; Bs[kq+6][r]=w1.z; Bs[kq+7][r]=w1.w;
        __syncthreads();
        #pragma unroll
        for (int kk = 0; kk < 16; ++kk) {
            float av[8], bv[8];
            *(float4*)&av[0] = *(const float4*)&As[kk][ty * 8];
            *(float4*)&av[4] = *(const float4*)&As[kk][ty * 8 + 4];
            *(float4*)&bv[0] = *(const float4*)&Bs[kk][tx * 8];
            *(float4*)&bv[4] = *(const float4*)&Bs[kk][tx * 8 + 4];
            #pragma unroll
            for (int i = 0; i < 8; ++i)
                #pragma unroll
                for (int j = 0; j < 8; ++j) acc[i][j] += av[i] * bv[j];
        }
    }
    #pragma unroll
    for (int i = 0; i < 8; ++i) {
        const int s = s0 + ty * 8 + i;
        #pragma unroll
        for (int jq = 0; jq < 2; ++jq) {
            const int o = o0 + tx * 8 + jq * 4;
            float4 v;
            v.x = acc[i][jq*4+0] + bias[o+0];
            v.y = acc[i][jq*4+1] + bias[o+1];
            v.z = acc[i][jq*4+2] + bias[o+2];
            v.w = acc[i][jq*4+3] + bias[o+3];
            *(float4*)&Y[(size_t)s * E_ + o] = v;
        }
    }
}

// ---------------------------------------------------------------------------
// Sc[h][i][j] = Q[h][i] . K[h][j] (bf16). Lower-tri tiles only. k-major LDS:
// transposed store (+1 pad, 2-way=free) so fragment reads are broadcast
// ds_read_b128: 2 reads : 16 FMA per kk (was 8 scalar reads : 16 FMA).
// ---------------------------------------------------------------------------
__global__ __launch_bounds__(256) void sc_gemm(const float* __restrict__ Q,
                                               const float* __restrict__ K,
                                               u16* __restrict__ Sc)
{
    const int h = blockIdx.z;
    const int jt = blockIdx.x, it = blockIdx.y;
    if (jt > it) return;
    const int i0 = it * 64, j0 = jt * 64;
    __shared__ float Qs[64][65];   // [k][m]
    __shared__ float Ks[64][65];   // [k][n]
    const float* Qh = Q + (size_t)h * S_ * D_;
    const float* Kh = K + (size_t)h * S_ * D_;
    const int tid = threadIdx.x;
    for (int idx = tid; idx < 1024; idx += 256) {
        const int rr = idx >> 4, c4 = (idx & 15) << 2;
        float4 q4 = *(const float4*)&Qh[(size_t)(i0 + rr) * D_ + c4];
        Qs[c4 + 0][rr] = q4.x; Qs[c4 + 1][rr] = q4.y; Qs[c4 + 2][rr] = q4.z; Qs[c4 + 3][rr] = q4.w;
        float4 k4 = *(const float4*)&Kh[(size_t)(j0 + rr) * D_ + c4];
        Ks[c4 + 0][rr] = k4.x; Ks[c4 + 1][rr] = k4.y; Ks[c4 + 2][rr] = k4.z; Ks[c4 + 3][rr] = k4.w;
    }
    __syncthreads();
    const int ty = tid >> 4, tx = tid & 15;
    float acc[4][4] = {};
    #pragma unroll 4
    for (int kk = 0; kk < 64; ++kk) {
        float4 a4 = *(const float4*)&Qs[kk][ty * 4];
        float4 b4 = *(const float4*)&Ks[kk][tx * 4];
        const float av[4] = {a4.x, a4.y, a4.z, a4.w};
        const float bv[4] = {b4.x, b4.y, b4.z, b4.w};
        #pragma unroll
        for (int i = 0; i < 4; ++i)
            #pragma unroll
            for (int j = 0; j < 4; ++j) acc[i][j] += av[i] * bv[j];
    }
    u16* out = Sc + ((size_t)h * S_ + i0) * S_ + j0;
    #pragma unroll
    for (int i = 0; i < 4; ++i)
        #pragma unroll
        for (int j = 0; j < 4; ++j)
            out[(size_t)(ty * 4 + i) * S_ + tx * 4 + j] = f2bf(acc[i][j]);
}

// ---------------------------------------------------------------------------
// prep_kernel: rsum per scan row + acc-init over rows 0..407 (global atomics).
// ---------------------------------------------------------------------------
__global__ __launch_bounds__(256) void prep_kernel(const u16* __restrict__ Sc,
                                                   float* __restrict__ rsumG,
                                                   float* __restrict__ accG)
{
    const int h = blockIdx.y;
    const int wave = threadIdx.x >> 6, lane = threadIdx.x & 63;
    const int bx = blockIdx.x;
    if (bx < NSCAN_ / 4) {
        const int tok = CB_ + bx * 4 + wave;
        const u16* row = Sc + ((size_t)h * S_ + tok) * S_ + (tok - RB_);
        float sm = 0.f;
        #pragma unroll
        for (int k = 0; k < 4; ++k) {
            const int j = k * 64 + lane;
            if (j <= RB_) sm += __expf(bf2f(row[j]));
        }
        const float z = wsum64(sm);
        if (lane == 0) rsumG[(size_t)h * NSCAN_ + tok - CB_] = z;
    } else {
        const int t = (bx - NSCAN_ / 4) * 4 + wave;   // 0..407
        const u16* row = Sc + ((size_t)h * S_ + t) * S_;
        float sm = 0.f;
        for (int c = lane; c <= t; c += 64) sm += __expf(bf2f(row[c]));
        const float z = wsum64(sm);
        const float w = __powf(PEN_, (float)(CB_ - 1 - t)) / z;
        for (int c = lane; c <= t; c += 64)
            atomicAdd(&accG[h * CB_ + c], __expf(bf2f(row[c])) * w);
    }
}

// ---------------------------------------------------------------------------
// H2O serial scan, one wave/head.
// Round-5 post-mortem fixes:
//  * vmcnt accounting: global STORES (heavy-list persist, 4/iter) also count
//    in vmcnt. vmcnt(12) was forcing retirement of loads issued 1 iter ago.
//    Ops newer than row tok+1's loads at the wait point: >=16 at every
//    iteration (3 load groups + store groups) -> vmcnt(16) is exact+safe.
//  * WAR hazard guard: s_waitcnt lgkmcnt(0) inside the issue block so a
//    global_load can never overwrite VGPRs an in-flight ds_write still
//    sources; staging moved mid-iter (gap to reissue ~250cy, was ~30cy).
// ---------------------------------------------------------------------------
__global__ __launch_bounds__(64, 1) void scan_kernel(const u16* __restrict__ Sc,
                                                     const float* __restrict__ accG,
                                                     const float* __restrict__ rsumG,
                                                     u16* __restrict__ heavyOut)
{
    const int h = blockIdx.x;
    const int lane = threadIdx.x;
    __shared__ float ring[256];
    __shared__ float rsumLDS[NSCAN_];
    __shared__ __align__(16) u16 rowbuf[2][S_];
    const u16* sch = Sc + (size_t)h * S_ * S_;
    const float* accH = accG + h * CB_;
    u16* hOutH = heavyOut + (size_t)h * NSCAN_ * HB_;

    for (int i = lane; i < NSCAN_; i += 64) rsumLDS[i] = rsumG[(size_t)h * NSCAN_ + i];
    for (int i = lane; i < RB_; i += 64) ring[(HB_ + i) & 255] = accH[HB_ + i];

    // heavy slots j=k*64+lane (valid j<204). lane63/k3 = slot 255 = candidate.
    const int slotc[4] = {lane, 64 + lane, 128 + lane, 192 + lane};
    int hcol[4]; float hacc[4];
    #pragma unroll
    for (int k = 0; k < 4; ++k) {
        const bool v = (slotc[k] < HB_);
        hcol[k] = v ? slotc[k] : 0;
        hacc[k] = v ? accH[slotc[k]] : POSINF;
    }

    // ---- asm prefetch machinery: buffer for row r is p[r&3] ----
    u32x4 p0[4], p1[4], p2[4], p3[4];
    #define ISSUE_ROW(BUF, ROWI)                                                 \
        do {                                                                     \
            const void* _ap = (const void*)((const char*)(sch + (size_t)(ROWI) * S_) + lane * 16); \
            asm volatile("s_waitcnt lgkmcnt(0)\n\t"                              \
                         "global_load_dwordx4 %0, %4, off\n\t"                   \
                         "global_load_dwordx4 %1, %4, off offset:1024\n\t"       \
                         "global_load_dwordx4 %2, %4, off offset:2048\n\t"       \
                         "global_load_dwordx4 %3, %4, off offset:3072"           \
                         : "=v"(BUF[0]), "=v"(BUF[1]), "=v"(BUF[2]), "=v"(BUF[3]) \
                         : "v"(_ap) : "memory");                                 \
        } while (0)
    #define WAIT_VM(N) asm volatile("s_waitcnt vmcnt(" #N ")" ::: "memory")

    // prologue: rows CB..CB+3 in flight; stage row CB into rowbuf[0]
    ISSUE_ROW(p0, CB_ + 0);
    ISSUE_ROW(p1, CB_ + 1);
    ISSUE_ROW(p2, CB_ + 2);
    ISSUE_ROW(p3, CB_ + 3);
    WAIT_VM(12);                       // 12 newer loads -> row CB done
    {
        u32x4* db = (u32x4*)rowbuf[0];
        #pragma unroll
        for (int j = 0; j < 4; ++j) db[j * 64 + lane] = p0[j];
    }

    float acc_cand;
    {   // ---- peeled tok = 408 (buf[408&3]=p0 freed -> row 412) ----
        ISSUE_ROW(p0, CB_ + 4);
        const u16* srow = rowbuf[0];
        float e[4]; float lsum = 0.f;
        #pragma unroll
        for (int k = 0; k < 4; ++k) {
            const bool v = (slotc[k] < HB_);
            e[k] = v ? __expf(bf2f(srow[hcol[k]])) : 0.f;
            lsum += e[k];
        }
        const float Z = wsum64(lsum) + rsumLDS[0];
        const float invZ = __fdividef(1.f, Z);
        #pragma unroll
        for (int k = 0; k < 4; ++k) hacc[k] = hacc[k] * PEN_ + e[k] * invZ;
        #pragma unroll
        for (int k = 0; k < 4; ++k)
            if (slotc[k] < HB_) hOutH[slotc[k]] = (u16)slotc[k];
        float nv0 = 0.f;
        #pragma unroll
        for (int k = 0; k < 4; ++k) {
            if (slotc[k] <= RB_) {
                const int col = HB_ + slotc[k];          // li = 204
                const float p = __expf(bf2f(srow[col])) * invZ;
                const float old = (col == CB_) ? 0.f : ring[col & 255];
                const float nv = old * PEN_ + p;
                ring[col & 255] = nv;
                if (k == 0) nv0 = nv;
            }
        }
        acc_cand = __int_as_float(__builtin_amdgcn_readlane(__float_as_int(nv0), 0));
        WAIT_VM(12);                   // newer: L410,L411,L412,S408 -> row 409 done
        u32x4* db = (u32x4*)rowbuf[1];
        #pragma unroll
        for (int j = 0; j < 4; ++j) db[j * 64 + lane] = p1[j];
    }

    auto iter = [&](int tok, u32x4 (&ld)[4], u32x4 (&st)[4]) {
        const int li = tok - RB_;
        // refill the buffer freed last iter with row tok+4 (lgkm guard inside)
        const int nr = (tok + 4 < S_) ? tok + 4 : S_ - 1;
        ISSUE_ROW(ld, nr);
        // insert candidate (col li-1, acc acc_cand) at slot 255
        if (lane == 63) { hcol[3] = li - 1; hacc[3] = acc_cand; }
        const float rsum = rsumLDS[tok - CB_];
        const u16* srow = rowbuf[tok & 1];

        // issue all LDS reads of the current row up front (latency overlapped
        // by the VALU-only f64 argmin below)
        float sg[4];
        #pragma unroll
        for (int k = 0; k < 4; ++k) sg[k] = bf2f(srow[hcol[k]]);
        float pwr[4], oldw[4];
        #pragma unroll
        for (int k = 0; k < 4; ++k) {
            if (slotc[k] <= RB_) {
                const int col = li + slotc[k];
                pwr[k] = bf2f(srow[col]);
                oldw[k] = (col == tok) ? 0.f : ring[col & 255];
            } else { pwr[k] = NEGINF; oldw[k] = 0.f; }
        }
        // single f64 argmin reduction (overlaps LDS latency)
        double key = __hiloint2double(0x7F800000, 0x7FFFFFFF);
        #pragma unroll
        for (int k = 0; k < 4; ++k) {
            const int lo = ((2047 - hcol[k]) << 8) | slotc[k];
            key = fmin(key, __hiloint2double(__float_as_int(hacc[k]), lo));
        }
        key = wmind64(key);
        // vm wait (exact bound incl. stores) + stage row tok+1 mid-iter
        WAIT_VM(16);
        {
            u32x4* db = (u32x4*)rowbuf[(tok + 1) & 1];
            #pragma unroll
            for (int j = 0; j < 4; ++j) db[j * 64 + lane] = st[j];
        }
        // exp + wave sum of heavy+candidate
        const bool v3 = (lane < HB_ - 192) || (lane == 63);
        float e[4]; float lsum = 0.f;
        #pragma unroll
        for (int k = 0; k < 4; ++k) {
            const bool v = (k < 3) || v3;
            e[k] = v ? __expf(sg[k]) : 0.f;
            lsum += e[k];
        }
        const float presum = wsum64(lsum);
        const int lo63 = __builtin_amdgcn_readlane(__double2loint(key), 63);
        const int slot = lo63 & 255;
        const int kb = slot >> 6, lb = slot & 63;
        const float esel = (kb == 0) ? e[0] : (kb == 1) ? e[1] : (kb == 2) ? e[2] : e[3];
        const float exp_bc = __int_as_float(__builtin_amdgcn_readlane(__float_as_int(esel), lb));
        const float exp_li1 = __int_as_float(__builtin_amdgcn_readlane(__float_as_int(e[3]), 63));
        const float Z = presum - exp_bc + rsum;
        const float invZ = __fdividef(1.f, Z);
        // replace dropped slot with candidate; update all heavy accs
        #pragma unroll
        for (int k = 0; k < 4; ++k) {
            const bool m = (slotc[k] == slot);
            const float base = m ? acc_cand : hacc[k];
            const float ee = m ? exp_li1 : e[k];
            hcol[k] = m ? (li - 1) : hcol[k];
            hacc[k] = base * PEN_ + ee * invZ;
        }
        // persist heavy set
        u16* hrow = hOutH + (size_t)(tok - CB_) * HB_;
        #pragma unroll
        for (int k = 0; k < 4; ++k)
            if (slotc[k] < HB_) hrow[slotc[k]] = (u16)hcol[k];
        // recent-window acc updates
        float nv0 = 0.f;
        #pragma unroll
        for (int k = 0; k < 4; ++k) {
            if (slotc[k] <= RB_) {
                const int col = li + slotc[k];
                const float nv = oldw[k] * PEN_ + __expf(pwr[k]) * invZ;
                ring[col & 255] = nv;
                if (k == 0) nv0 = nv;
            }
        }
        acc_cand = __int_as_float(__builtin_amdgcn_readlane(__float_as_int(nv0), 0));
    };

    for (int tok = CB_ + 1; tok + 3 < S_; tok += 4) {   // 409..2044
        iter(tok + 0, p1, p2);
        iter(tok + 1, p2, p3);
        iter(tok + 2, p3, p0);
        iter(tok + 3, p0, p1);
    }
    iter(S_ - 3, p1, p2);
    iter(S_ - 2, p2, p3);
    iter(S_ - 1, p3, p0);
    #undef ISSUE_ROW
    #undef WAIT_VM
}

// ---------------------------------------------------------------------------
// Final sparse attention: one block per (head,row).
// ---------------------------------------------------------------------------
__global__ __launch_bounds__(256) void attn_out(const u16* __restrict__ Sc,
                                                const float* __restrict__ V,
                                                const u16* __restrict__ heavyIn,
                                                float* __restrict__ O)
{
    const int bid = blockIdx.x;
    const int h = ((bid & 7) << 1) | ((bid >> 3) & 1);
    const int r = bid >> 4;
    const int tid = threadIdx.x;
    const int lane = tid & 63, wave = tid >> 6;
    __shared__ float sbuf[416];
    __shared__ u16 cbuf[416];
    __shared__ float wred[4];
    __shared__ float opart[4][64];
    const u16* srow = Sc + ((size_t)h * S_ + r) * S_;
    const int li = r - RB_;
    const int nact = (r < CB_) ? (r + 1) : (HB_ + RB_ + 1);
    const u16* hrow = (r < CB_) ? (const u16*)0
                                : heavyIn + ((size_t)h * NSCAN_ + (r - CB_)) * HB_;
    float lm = NEGINF;
    for (int i = tid; i < nact; i += 256) {
        int col;
        if (r < CB_) col = i;
        else col = (i < HB_) ? (int)hrow[i] : li + (i - HB_);
        const float s = bf2f(srow[col]);
        sbuf[i] = s; cbuf[i] = (u16)col;
        lm = fmaxf(lm, s);
    }
    #pragma unroll
    for (int o = 32; o > 0; o >>= 1) lm = fmaxf(lm, __shfl_xor(lm, o));
    if (lane == 0) wred[wave] = lm;
    __syncthreads();
    const float mx = fmaxf(fmaxf(wred[0], wred[1]), fmaxf(wred[2], wred[3]));
    __syncthreads();
    float ls = 0.f;
    for (int i = tid; i < nact; i += 256) {
        const float p = __expf(sbuf[i] - mx);
        sbuf[i] = p;
        ls += p;
    }
    #pragma unroll
    for (int o = 32; o > 0; o >>= 1) ls += __shfl_xor(ls, o);
    if (lane == 0) wred[wave] = ls;
    __syncthreads();
    const float Z = wred[0] + wred[1] + wred[2] + wred[3];
    float oacc = 0.f;
    const float* vh = V + (size_t)h * S_ * D_;
    for (int i = wave; i < nact; i += 4)
        oacc += sbuf[i] * vh[(size_t)cbuf[i] * D_ + lane];
    opart[wave][lane] = oacc;
    __syncthreads();
    if (tid < 64) {
        const float tot = (opart[0][tid] + opart[1][tid] + opart[2][tid] + opart[3][tid]) / Z;
        O[(size_t)r * E_ + h * D_ + tid] = tot;
    }
}

// ---------------------------------------------------------------------------
extern "C" void kernel_launch(void* const* d_in, const int* in_sizes, int n_in,
                              void* d_out, int out_size, void* d_ws, size_t ws_size,
                              hipStream_t stream)
{
    const float* hs = (const float*)d_in[0];
    const float* Wq = (const float*)d_in[2];
    const float* bq = (const float*)d_in[3];
    const float* Wk = (const float*)d_in[4];
    const float* bk = (const float*)d_in[5];
    const float* Wv = (const float*)d_in[6];
    const float* bv = (const float*)d_in[7];
    const float* Wo = (const float*)d_in[8];
    const float* bo = (const float*)d_in[9];

    char* ws = (char*)d_ws;
    const size_t MB = 1024 * 1024;
    float* Q     = (float*)(ws);                   //   8 MB [H][S][D]
    float* K     = (float*)(ws + 8 * MB);          //   8 MB
    float* V     = (float*)(ws + 16 * MB);         //   8 MB
    u16*   Sc    = (u16*)  (ws + 24 * MB);         // 128 MB [H][S][S] bf16
    u16*   hvy   = (u16*)  (ws + 152 * MB);        // ~10.2 MB [H][NSCAN][HB]
    float* rsumG = (float*)(ws + 163 * MB);        // 105 KB [H][NSCAN]
    float* accG  = (float*)(ws + 164 * MB);        //  26 KB [H][CB]
    float* O     = (float*)(ws + 168 * MB);        //   8 MB [S][E]
    (void)ws_size; (void)in_sizes; (void)n_in; (void)out_size;

    (void)hipMemsetAsync(accG, 0, (size_t)H_ * CB_ * sizeof(float), stream);
    qkv_gemm<<<dim3(8, 16, 3), 256, 0, stream>>>(hs, Wq, bq, Wk, bk, Wv, bv, Q, K, V);
    sc_gemm <<<dim3(32, 32, 16), 256, 0, stream>>>(Q, K, Sc);
    prep_kernel<<<dim3(NSCAN_ / 4 + CB_ / 4, H_), 256, 0, stream>>>(Sc, rsumG, accG);
    scan_kernel<<<16, 64, 0, stream>>>(Sc, accG, rsumG, hvy);
    attn_out<<<32768, 256, 0, stream>>>(Sc, V, hvy, O);
    proj_gemm<<<dim3(8, 16, 1), 256, 0, stream>>>(O, Wo, bo, (float*)d_out);
}

// Round 9
// 1855.864 us; speedup vs baseline: 1.5124x; 1.2080x over previous
//
#include <hip/hip_runtime.h>

#define S_ 2048
#define E_ 1024
#define H_ 16
#define D_ 64
#define HB_ 204
#define RB_ 204
#define CB_ 408
#define NSCAN_ (S_ - CB_)
#define PEN_ 0.99f
#define NEGINF (-__builtin_huge_valf())
#define POSINF (__builtin_huge_valf())

typedef unsigned short u16;
typedef unsigned int u32;
typedef unsigned int u32x4 __attribute__((ext_vector_type(4)));

__device__ __forceinline__ float bf2f(u16 u) {
    union { u32 u; float f; } a; a.u = ((u32)u) << 16; return a.f;
}
__device__ __forceinline__ u16 f2bf(float f) {
    union { float f; u32 u; } a; a.f = f;
    u32 r = (a.u + 0x7FFFu + ((a.u >> 16) & 1u)) >> 16;
    return (u16)r;
}

// ---------------------------------------------------------------------------
// Wave64 reductions via DPP. wsum64: result broadcast. wmind64: min in lane63.
// ---------------------------------------------------------------------------
#define DPPF(ID, V, CTRL, RMASK) \
    __int_as_float(__builtin_amdgcn_update_dpp(__float_as_int(ID), __float_as_int(V), CTRL, RMASK, 0xf, false))

__device__ __forceinline__ float wsum64(float v) {
    float t;
    t = DPPF(0.f, v, 0x111, 0xf); v += t;
    t = DPPF(0.f, v, 0x112, 0xf); v += t;
    t = DPPF(0.f, v, 0x114, 0xf); v += t;
    t = DPPF(0.f, v, 0x118, 0xf); v += t;
    t = DPPF(0.f, v, 0x142, 0xa); v += t;
    t = DPPF(0.f, v, 0x143, 0xc); v += t;
    return __int_as_float(__builtin_amdgcn_readlane(__float_as_int(v), 63));
}
// f64 min reduction: key doubles are positive/finite; identity = +inf double.
template <int CTRL, int RMASK>
__device__ __forceinline__ double dmin_step(double v) {
    const int lo = __double2loint(v), hi = __double2hiint(v);
    const int slo = __builtin_amdgcn_update_dpp(0, lo, CTRL, RMASK, 0xf, false);
    const int shi = __builtin_amdgcn_update_dpp(0x7FF00000, hi, CTRL, RMASK, 0xf, false);
    return fmin(v, __hiloint2double(shi, slo));
}
__device__ __forceinline__ double wmind64(double v) {
    v = dmin_step<0x111, 0xf>(v);
    v = dmin_step<0x112, 0xf>(v);
    v = dmin_step<0x114, 0xf>(v);
    v = dmin_step<0x118, 0xf>(v);
    v = dmin_step<0x142, 0xa>(v);   // row_bcast15
    v = dmin_step<0x143, 0xc>(v);   // row_bcast31
    return v;                        // lane 63 holds the wave min
}

// ---------------------------------------------------------------------------
// QKV projection: X[S,E] @ W^T + b -> head-major [H][S][D] f32.
// ---------------------------------------------------------------------------
__global__ __launch_bounds__(256) void qkv_gemm(
    const float* __restrict__ X,
    const float* __restrict__ W0, const float* __restrict__ b0,
    const float* __restrict__ W1, const float* __restrict__ b1,
    const float* __restrict__ W2, const float* __restrict__ b2,
    float* __restrict__ Q, float* __restrict__ K, float* __restrict__ V)
{
    const int z = blockIdx.z;
    const float* W    = (z == 0) ? W0 : (z == 1) ? W1 : W2;
    const float* bias = (z == 0) ? b0 : (z == 1) ? b1 : b2;
    float* dst        = (z == 0) ? Q  : (z == 1) ? K  : V;
    const int o0 = blockIdx.x * 128, s0 = blockIdx.y * 128;
    __shared__ float As[16][132];   // [k][m]
    __shared__ float Bs[16][132];   // [k][n]
    const int tid = threadIdx.x;
    const int ty = tid >> 4, tx = tid & 15;
    const int r = tid >> 1, kq = (tid & 1) << 3;
    float acc[8][8] = {};
    for (int kb = 0; kb < E_; kb += 16) {
        float4 a0 = *(const float4*)&X[(size_t)(s0 + r) * E_ + kb + kq];
        float4 a1 = *(const float4*)&X[(size_t)(s0 + r) * E_ + kb + kq + 4];
        float4 w0 = *(const float4*)&W[(size_t)(o0 + r) * E_ + kb + kq];
        float4 w1 = *(const float4*)&W[(size_t)(o0 + r) * E_ + kb + kq + 4];
        __syncthreads();
        As[kq+0][r]=a0.x; As[kq+1][r]=a0.y; As[kq+2][r]=a0.z; As[kq+3][r]=a0.w;
        As[kq+4][r]=a1.x; As[kq+5][r]=a1.y; As[kq+6][r]=a1.z; As[kq+7][r]=a1.w;
        Bs[kq+0][r]=w0.x; Bs[kq+1][r]=w0.y; Bs[kq+2][r]=w0.z; Bs[kq+3][r]=w0.w;
        Bs[kq+4][r]=w1.x; Bs[kq+5][r]=w1.y; Bs[kq+6][r]=w1.z; Bs[kq+7][r]=w1.w;
        __syncthreads();
        #pragma unroll
        for (int kk = 0; kk < 16; ++kk) {
            float av[8], bv[8];
            *(float4*)&av[0] = *(const float4*)&As[kk][ty * 8];
            *(float4*)&av[4] = *(const float4*)&As[kk][ty * 8 + 4];
            *(float4*)&bv[0] = *(const float4*)&Bs[kk][tx * 8];
            *(float4*)&bv[4] = *(const float4*)&Bs[kk][tx * 8 + 4];
            #pragma unroll
            for (int i = 0; i < 8; ++i)
                #pragma unroll
                for (int j = 0; j < 8; ++j) acc[i][j] += av[i] * bv[j];
        }
    }
    #pragma unroll
    for (int i = 0; i < 8; ++i) {
        const int s = s0 + ty * 8 + i;
        #pragma unroll
        for (int jq = 0; jq < 2; ++jq) {
            const int o = o0 + tx * 8 + jq * 4;
            float4 v;
            v.x = acc[i][jq*4+0] + bias[o+0];
            v.y = acc[i][jq*4+1] + bias[o+1];
            v.z = acc[i][jq*4+2] + bias[o+2];
            v.w = acc[i][jq*4+3] + bias[o+3];
            if (z == 0) { v.x *= 0.125f; v.y *= 0.125f; v.z *= 0.125f; v.w *= 0.125f; }
            *(float4*)&dst[((size_t)(o >> 6) * S_ + s) * D_ + (o & 63)] = v;
        }
    }
}

// ---------------------------------------------------------------------------
// Output projection: Y[S,E] = X[S,E] @ Wo^T + bo
// ---------------------------------------------------------------------------
__global__ __launch_bounds__(256) void proj_gemm(
    const float* __restrict__ X, const float* __restrict__ W,
    const float* __restrict__ bias, float* __restrict__ Y)
{
    const int o0 = blockIdx.x * 128, s0 = blockIdx.y * 128;
    __shared__ float As[16][132];
    __shared__ float Bs[16][132];
    const int tid = threadIdx.x;
    const int ty = tid >> 4, tx = tid & 15;
    const int r = tid >> 1, kq = (tid & 1) << 3;
    float acc[8][8] = {};
    for (int kb = 0; kb < E_; kb += 16) {
        float4 a0 = *(const float4*)&X[(size_t)(s0 + r) * E_ + kb + kq];
        float4 a1 = *(const float4*)&X[(size_t)(s0 + r) * E_ + kb + kq + 4];
        float4 w0 = *(const float4*)&W[(size_t)(o0 + r) * E_ + kb + kq];
        float4 w1 = *(const float4*)&W[(size_t)(o0 + r) * E_ + kb + kq + 4];
        __syncthreads();
        As[kq+0][r]=a0.x; As[kq+1][r]=a0.y; As[kq+2][r]=a0.z; As[kq+3][r]=a0.w;
        As[kq+4][r]=a1.x; As[kq+5][r]=a1.y; As[kq+6][r]=a1.z; As[kq+7][r]=a1.w;
        Bs[kq+0][r]=w0.x; Bs[kq+1][r]=w0.y; Bs[kq+2][r]=w0.z; Bs[kq+3][r]=w0.w;
        Bs[kq+4][r]=w1.x; Bs[kq+5][r]=w1.y; Bs[kq+6][r]=w1.z; Bs[kq+7][r]=w1.w;
        __syncthreads();
        #pragma unroll
        for (int kk = 0; kk < 16; ++kk) {
            float av[8], bv[8];
            *(float4*)&av[0] = *(const float4*)&As[kk][ty * 8];
            *(float4*)&av[4] = *(const float4*)&As[kk][ty * 8 + 4];
            *(float4*)&bv[0] = *(const float4*)&Bs[kk][tx * 8];
            *(float4*)&bv[4] = *(const float4*)&Bs[kk][tx * 8 + 4];
            #pragma unroll
            for (int i = 0; i < 8; ++i)
                #pragma unroll
                for (int j = 0; j < 8; ++j) acc[i][j] += av[i] * bv[j];
        }
    }
    #pragma unroll
    for (int i = 0; i < 8; ++i) {
        const int s = s0 + ty * 8 + i;
        #pragma unroll
        for (int jq = 0; jq < 2; ++jq) {
            const int o = o0 + tx * 8 + jq * 4;
            float4 v;
            v.x = acc[i][jq*4+0] + bias[o+0];
            v.y = acc[i][jq*4+1] + bias[o+1];
            v.z = acc[i][jq*4+2] + bias[o+2];
            v.w = acc[i][jq*4+3] + bias[o+3];
            *(float4*)&Y[(size_t)s * E_ + o] = v;
        }
    }
}

// ---------------------------------------------------------------------------
// Sc[h][i][j] = Q[h][i] . K[h][j] (bf16). Lower-tri tiles only. k-major LDS.
// ---------------------------------------------------------------------------
__global__ __launch_bounds__(256) void sc_gemm(const float* __restrict__ Q,
                                               const float* __restrict__ K,
                                               u16* __restrict__ Sc)
{
    const int h = blockIdx.z;
    const int jt = blockIdx.x, it = blockIdx.y;
    if (jt > it) return;
    const int i0 = it * 64, j0 = jt * 64;
    __shared__ float Qs[64][65];   // [k][m]
    __shared__ float Ks[64][65];   // [k][n]
    const float* Qh = Q + (size_t)h * S_ * D_;
    const float* Kh = K + (size_t)h * S_ * D_;
    const int tid = threadIdx.x;
    for (int idx = tid; idx < 1024; idx += 256) {
        const int rr = idx >> 4, c4 = (idx & 15) << 2;
        float4 q4 = *(const float4*)&Qh[(size_t)(i0 + rr) * D_ + c4];
        Qs[c4 + 0][rr] = q4.x; Qs[c4 + 1][rr] = q4.y; Qs[c4 + 2][rr] = q4.z; Qs[c4 + 3][rr] = q4.w;
        float4 k4 = *(const float4*)&Kh[(size_t)(j0 + rr) * D_ + c4];
        Ks[c4 + 0][rr] = k4.x; Ks[c4 + 1][rr] = k4.y; Ks[c4 + 2][rr] = k4.z; Ks[c4 + 3][rr] = k4.w;
    }
    __syncthreads();
    const int ty = tid >> 4, tx = tid & 15;
    float acc[4][4] = {};
    #pragma unroll 4
    for (int kk = 0; kk < 64; ++kk) {
        float4 a4 = *(const float4*)&Qs[kk][ty * 4];
        float4 b4 = *(const float4*)&Ks[kk][tx * 4];
        const float av[4] = {a4.x, a4.y, a4.z, a4.w};
        const float bv[4] = {b4.x, b4.y, b4.z, b4.w};
        #pragma unroll
        for (int i = 0; i < 4; ++i)
            #pragma unroll
            for (int j = 0; j < 4; ++j) acc[i][j] += av[i] * bv[j];
    }
    u16* out = Sc + ((size_t)h * S_ + i0) * S_ + j0;
    #pragma unroll
    for (int i = 0; i < 4; ++i)
        #pragma unroll
        for (int j = 0; j < 4; ++j)
            out[(size_t)(ty * 4 + i) * S_ + tx * 4 + j] = f2bf(acc[i][j]);
}

// ---------------------------------------------------------------------------
// prep_kernel: rsum per scan row + acc-init over rows 0..407 (global atomics).
// ---------------------------------------------------------------------------
__global__ __launch_bounds__(256) void prep_kernel(const u16* __restrict__ Sc,
                                                   float* __restrict__ rsumG,
                                                   float* __restrict__ accG)
{
    const int h = blockIdx.y;
    const int wave = threadIdx.x >> 6, lane = threadIdx.x & 63;
    const int bx = blockIdx.x;
    if (bx < NSCAN_ / 4) {
        const int tok = CB_ + bx * 4 + wave;
        const u16* row = Sc + ((size_t)h * S_ + tok) * S_ + (tok - RB_);
        float sm = 0.f;
        #pragma unroll
        for (int k = 0; k < 4; ++k) {
            const int j = k * 64 + lane;
            if (j <= RB_) sm += __expf(bf2f(row[j]));
        }
        const float z = wsum64(sm);
        if (lane == 0) rsumG[(size_t)h * NSCAN_ + tok - CB_] = z;
    } else {
        const int t = (bx - NSCAN_ / 4) * 4 + wave;   // 0..407
        const u16* row = Sc + ((size_t)h * S_ + t) * S_;
        float sm = 0.f;
        for (int c = lane; c <= t; c += 64) sm += __expf(bf2f(row[c]));
        const float z = wsum64(sm);
        const float w = __powf(PEN_, (float)(CB_ - 1 - t)) / z;
        for (int c = lane; c <= t; c += 64)
            atomicAdd(&accG[h * CB_ + c], __expf(bf2f(row[c])) * w);
    }
}

// ---------------------------------------------------------------------------
// MERGED kernel: 16 scan blocks + all scan-independent attention blocks in
// one launch (keeps SCLK up during the serial scan; removes attn_out from
// the critical path). No cross-block dependencies -> dispatch-order safe.
// r8 crash root-cause: SCAN_ITER macro declared `const int tok = (TOK)` and
// was invoked as SCAN_ITER(tok+0,...) inside `for(int tok...)` -> the inner
// tok initialized FROM ITSELF (uninitialized) -> wild loads -> fault. All
// macro internals now _si_-prefixed. asm outputs are "=&v" (early-clobber:
// plain "=v" let an output quad alias the address pair still live for
// instructions 2-4 of the block).
// ---------------------------------------------------------------------------
#define NFULL_ (CB_ * H_)          /* 6528  full-attn blocks (r<CB)  */
#define NPART_ (NSCAN_ * H_)       /* 26240 recent-partial blocks    */

__global__ __launch_bounds__(256) void scan_fill(const u16* __restrict__ Sc,
                                                 const float* __restrict__ accG,
                                                 const float* __restrict__ rsumG,
                                                 u16* __restrict__ heavyOut,
                                                 const float* __restrict__ V,
                                                 float* __restrict__ O)
{
    __shared__ __align__(16) char ldsPool[15872];
    const int bid = blockIdx.x;
    const int tid = threadIdx.x;

    if (bid >= 16) {
        // ---------------- fill paths: dense attention work ----------------
        float* sbuf  = (float*)ldsPool;            // up to 416 f32
        float* wred  = (float*)(ldsPool + 1664);   // 4 f32
        float* opart = (float*)(ldsPool + 1696);   // 256 f32
        const int lane = tid & 63, wave = tid >> 6;
        int h, r, c0, n;
        bool partial;
        if (bid < 16 + NFULL_) {                   // r < CB: full causal row
            const int t2 = bid - 16;
            r = t2 >> 4; h = t2 & 15;
            c0 = 0; n = r + 1; partial = false;
        } else {                                   // r >= CB: recent window only
            const int idx = bid - 16 - NFULL_;
            r = CB_ + (idx >> 4); h = idx & 15;
            c0 = r - RB_; n = RB_ + 1; partial = true;
        }
        const u16* srow = Sc + ((size_t)h * S_ + r) * S_;
        float ls = 0.f;
        for (int i = tid; i < n; i += 256) {
            const float p = __expf(bf2f(srow[c0 + i]));
            sbuf[i] = p; ls += p;
        }
        ls = wsum64(ls);
        if (lane == 0) wred[wave] = ls;
        __syncthreads();
        const float Z = wred[0] + wred[1] + wred[2] + wred[3];
        float pv = 0.f;
        const float* vh = V + (size_t)h * S_ * D_;
        for (int i = wave; i < n; i += 4)
            pv += sbuf[i] * vh[(size_t)(c0 + i) * D_ + lane];
        opart[wave * 64 + lane] = pv;
        __syncthreads();
        if (tid < 64) {
            const float tot = opart[tid] + opart[64 + tid] + opart[128 + tid] + opart[192 + tid];
            // partial rows: store UNNORMALIZED; heavy_merge adds + divides
            O[(size_t)r * E_ + h * D_ + tid] = partial ? tot : (tot / Z);
        }
        return;
    }

    // ---------------- scan path: one wave per head ----------------
    if (tid >= 64) return;
    const int h = bid;
    const int lane = tid;
    float* ring    = (float*)ldsPool;             // 256 f32
    float* rsumLDS = (float*)(ldsPool + 1024);    // NSCAN f32 (6560 B)
    u16*   rowbufA = (u16*)(ldsPool + 7584);      // 2048 u16
    u16*   rowbufB = rowbufA + S_;                // 2048 u16
    const u16* sch = Sc + (size_t)h * S_ * S_;
    const float* accH = accG + h * CB_;
    u16* hOutH = heavyOut + (size_t)h * NSCAN_ * HB_;

    for (int i = lane; i < NSCAN_; i += 64) rsumLDS[i] = rsumG[(size_t)h * NSCAN_ + i];
    for (int i = lane; i < RB_; i += 64) ring[(HB_ + i) & 255] = accH[HB_ + i];

    const int slotc[4] = {lane, 64 + lane, 128 + lane, 192 + lane};
    int hcol[4]; float hacc[4];
    #pragma unroll
    for (int k = 0; k < 4; ++k) {
        const bool v = (slotc[k] < HB_);
        hcol[k] = v ? slotc[k] : 0;
        hacc[k] = v ? accH[slotc[k]] : POSINF;
    }

    u32x4 p0[4], p1[4], p2[4], p3[4];
    #define ISSUE_ROW(BUF, ROWI)                                                 \
        do {                                                                     \
            const void* _ap = (const void*)((const char*)(sch + (size_t)(ROWI) * S_) + lane * 16); \
            asm volatile("s_waitcnt lgkmcnt(0)\n\t"                              \
                         "global_load_dwordx4 %0, %4, off\n\t"                   \
                         "global_load_dwordx4 %1, %4, off offset:1024\n\t"       \
                         "global_load_dwordx4 %2, %4, off offset:2048\n\t"       \
                         "global_load_dwordx4 %3, %4, off offset:3072"           \
                         : "=&v"(BUF[0]), "=&v"(BUF[1]), "=&v"(BUF[2]), "=&v"(BUF[3]) \
                         : "v"(_ap) : "memory");                                 \
        } while (0)
    #define WAIT_VM(N) asm volatile("s_waitcnt vmcnt(" #N ")" ::: "memory")

    ISSUE_ROW(p0, CB_ + 0);
    ISSUE_ROW(p1, CB_ + 1);
    ISSUE_ROW(p2, CB_ + 2);
    ISSUE_ROW(p3, CB_ + 3);
    WAIT_VM(12);
    {
        u32x4* db = (u32x4*)rowbufA;
        #pragma unroll
        for (int j = 0; j < 4; ++j) db[j * 64 + lane] = p0[j];
    }

    float acc_cand;
    {   // peeled tok = 408
        ISSUE_ROW(p0, CB_ + 4);
        const u16* srow = rowbufA;
        float e[4]; float lsum = 0.f;
        #pragma unroll
        for (int k = 0; k < 4; ++k) {
            const bool v = (slotc[k] < HB_);
            e[k] = v ? __expf(bf2f(srow[hcol[k]])) : 0.f;
            lsum += e[k];
        }
        const float Z = wsum64(lsum) + rsumLDS[0];
        const float invZ = __fdividef(1.f, Z);
        #pragma unroll
        for (int k = 0; k < 4; ++k) hacc[k] = hacc[k] * PEN_ + e[k] * invZ;
        #pragma unroll
        for (int k = 0; k < 4; ++k)
            if (slotc[k] < HB_) hOutH[slotc[k]] = (u16)slotc[k];
        float nv0 = 0.f;
        #pragma unroll
        for (int k = 0; k < 4; ++k) {
            if (slotc[k] <= RB_) {
                const int col = HB_ + slotc[k];
                const float p = __expf(bf2f(srow[col])) * invZ;
                const float old = (col == CB_) ? 0.f : ring[col & 255];
                const float nv = old * PEN_ + p;
                ring[col & 255] = nv;
                if (k == 0) nv0 = nv;
            }
        }
        acc_cand = __int_as_float(__builtin_amdgcn_readlane(__float_as_int(nv0), 0));
        WAIT_VM(12);
        u32x4* db = (u32x4*)rowbufB;
        #pragma unroll
        for (int j = 0; j < 4; ++j) db[j * 64 + lane] = p1[j];
    }

    // All internals _si_-prefixed: NO identifier can capture a call-site name.
    #define SCAN_ITER(TOK, LD, ST)                                               \
    do {                                                                         \
        const int _si_tok = (TOK);                                               \
        const int _si_li = _si_tok - RB_;                                        \
        const int _si_nr = (_si_tok + 4 < S_) ? _si_tok + 4 : S_ - 1;            \
        ISSUE_ROW(LD, _si_nr);                                                   \
        if (lane == 63) { hcol[3] = _si_li - 1; hacc[3] = acc_cand; }            \
        const float _si_rsum = rsumLDS[_si_tok - CB_];                           \
        const u16* _si_srow = (_si_tok & 1) ? rowbufB : rowbufA;                 \
        float _si_sg[4];                                                         \
        _Pragma("unroll")                                                        \
        for (int _si_k = 0; _si_k < 4; ++_si_k) _si_sg[_si_k] = bf2f(_si_srow[hcol[_si_k]]); \
        float _si_pwr[4], _si_oldw[4];                                           \
        _Pragma("unroll")                                                        \
        for (int _si_k = 0; _si_k < 4; ++_si_k) {                                \
            if (slotc[_si_k] <= RB_) {                                           \
                const int _si_col = _si_li + slotc[_si_k];                       \
                _si_pwr[_si_k] = bf2f(_si_srow[_si_col]);                        \
                _si_oldw[_si_k] = (_si_col == _si_tok) ? 0.f : ring[_si_col & 255]; \
            } else { _si_pwr[_si_k] = NEGINF; _si_oldw[_si_k] = 0.f; }           \
        }                                                                        \
        double _si_key = __hiloint2double(0x7F800000, 0x7FFFFFFF);               \
        _Pragma("unroll")                                                        \
        for (int _si_k = 0; _si_k < 4; ++_si_k) {                                \
            const int _si_lo = ((2047 - hcol[_si_k]) << 8) | slotc[_si_k];       \
            _si_key = fmin(_si_key, __hiloint2double(__float_as_int(hacc[_si_k]), _si_lo)); \
        }                                                                        \
        _si_key = wmind64(_si_key);                                              \
        WAIT_VM(12);                                                             \
        {                                                                        \
            u32x4* _si_db = (u32x4*)(((_si_tok + 1) & 1) ? rowbufB : rowbufA);   \
            _Pragma("unroll")                                                    \
            for (int _si_j = 0; _si_j < 4; ++_si_j) _si_db[_si_j * 64 + lane] = (ST)[_si_j]; \
        }                                                                        \
        const bool _si_v3 = (lane < HB_ - 192) || (lane == 63);                  \
        float _si_e[4]; float _si_lsum = 0.f;                                    \
        _Pragma("unroll")                                                        \
        for (int _si_k = 0; _si_k < 4; ++_si_k) {                                \
            const bool _si_v = (_si_k < 3) || _si_v3;                            \
            _si_e[_si_k] = _si_v ? __expf(_si_sg[_si_k]) : 0.f;                  \
            _si_lsum += _si_e[_si_k];                                            \
        }                                                                        \
        const float _si_presum = wsum64(_si_lsum);                               \
        const int _si_lo63 = __builtin_amdgcn_readlane(__double2loint(_si_key), 63); \
        const int _si_slot = _si_lo63 & 255;                                     \
        const int _si_kb = _si_slot >> 6, _si_lb = _si_slot & 63;                \
        const float _si_esel = (_si_kb == 0) ? _si_e[0] : (_si_kb == 1) ? _si_e[1] : (_si_kb == 2) ? _si_e[2] : _si_e[3]; \
        const float _si_exp_bc = __int_as_float(__builtin_amdgcn_readlane(__float_as_int(_si_esel), _si_lb)); \
        const float _si_exp_li1 = __int_as_float(__builtin_amdgcn_readlane(__float_as_int(_si_e[3]), 63)); \
        const float _si_Z = _si_presum - _si_exp_bc + _si_rsum;                  \
        const float _si_invZ = __fdividef(1.f, _si_Z);                           \
        _Pragma("unroll")                                                        \
        for (int _si_k = 0; _si_k < 4; ++_si_k) {                                \
            const bool _si_m = (slotc[_si_k] == _si_slot);                       \
            const float _si_base = _si_m ? acc_cand : hacc[_si_k];               \
            const float _si_ee = _si_m ? _si_exp_li1 : _si_e[_si_k];             \
            hcol[_si_k] = _si_m ? (_si_li - 1) : hcol[_si_k];                    \
            hacc[_si_k] = _si_base * PEN_ + _si_ee * _si_invZ;                   \
        }                                                                        \
        u16* _si_hrow = hOutH + (size_t)(_si_tok - CB_) * HB_;                   \
        _Pragma("unroll")                                                        \
        for (int _si_k = 0; _si_k < 4; ++_si_k)                                  \
            if (slotc[_si_k] < HB_) _si_hrow[slotc[_si_k]] = (u16)hcol[_si_k];   \
        float _si_nv0 = 0.f;                                                     \
        _Pragma("unroll")                                                        \
        for (int _si_k = 0; _si_k < 4; ++_si_k) {                                \
            if (slotc[_si_k] <= RB_) {                                           \
                const int _si_col = _si_li + slotc[_si_k];                       \
                const float _si_nv = _si_oldw[_si_k] * PEN_ + __expf(_si_pwr[_si_k]) * _si_invZ; \
                ring[_si_col & 255] = _si_nv;                                    \
                if (_si_k == 0) _si_nv0 = _si_nv;                                \
            }                                                                    \
        }                                                                        \
        acc_cand = __int_as_float(__builtin_amdgcn_readlane(__float_as_int(_si_nv0), 0)); \
    } while (0)

    SCAN_ITER(CB_ + 1, p1, p2);
    SCAN_ITER(CB_ + 2, p2, p3);
    SCAN_ITER(CB_ + 3, p3, p0);
    SCAN_ITER(CB_ + 4, p0, p1);
    for (int tokBase = CB_ + 5; tokBase + 3 < S_; tokBase += 4) {   // 413..2044
        SCAN_ITER(tokBase + 0, p1, p2);
        SCAN_ITER(tokBase + 1, p2, p3);
        SCAN_ITER(tokBase + 2, p3, p0);
        SCAN_ITER(tokBase + 3, p0, p1);
    }
    SCAN_ITER(S_ - 3, p1, p2);
    SCAN_ITER(S_ - 2, p2, p3);
    SCAN_ITER(S_ - 1, p3, p0);
    #undef SCAN_ITER
    #undef ISSUE_ROW
    #undef WAIT_VM
}

// ---------------------------------------------------------------------------
// heavy_merge: rows r>=CB. Gather 204 heavy cols, add to the recent-window
// partial already in O, normalize by (heavy sum + rsumG).
// ---------------------------------------------------------------------------
__global__ __launch_bounds__(256) void heavy_merge(const u16* __restrict__ Sc,
                                                   const float* __restrict__ V,
                                                   const u16* __restrict__ heavyIn,
                                                   const float* __restrict__ rsumG,
                                                   float* __restrict__ O)
{
    const int idx = blockIdx.x;
    const int r = CB_ + (idx >> 4), h = idx & 15;
    const int tid = threadIdx.x;
    const int lane = tid & 63, wave = tid >> 6;
    __shared__ float sbuf[208];
    __shared__ u16 cbuf[208];
    __shared__ float wred[4];
    __shared__ float opart[4][64];
    const u16* srow = Sc + ((size_t)h * S_ + r) * S_;
    const u16* hrow = heavyIn + ((size_t)h * NSCAN_ + (r - CB_)) * HB_;
    float ls = 0.f;
    for (int i = tid; i < HB_; i += 256) {
        const int col = hrow[i];
        const float p = __expf(bf2f(srow[col]));
        sbuf[i] = p; cbuf[i] = (u16)col;
        ls += p;
    }
    ls = wsum64(ls);
    if (lane == 0) wred[wave] = ls;
    __syncthreads();
    const float Z = wred[0] + wred[1] + wred[2] + wred[3]
                  + rsumG[(size_t)h * NSCAN_ + r - CB_];
    float pv = 0.f;
    const float* vh = V + (size_t)h * S_ * D_;
    for (int i = wave; i < HB_; i += 4)
        pv += sbuf[i] * vh[(size_t)cbuf[i] * D_ + lane];
    opart[wave][lane] = pv;
    __syncthreads();
    if (tid < 64) {
        const float tot = opart[0][tid] + opart[1][tid] + opart[2][tid] + opart[3][tid];
        float* op = &O[(size_t)r * E_ + h * D_ + tid];
        *op = (*op + tot) / Z;
    }
}

// ---------------------------------------------------------------------------
extern "C" void kernel_launch(void* const* d_in, const int* in_sizes, int n_in,
                              void* d_out, int out_size, void* d_ws, size_t ws_size,
                              hipStream_t stream)
{
    const float* hs = (const float*)d_in[0];
    const float* Wq = (const float*)d_in[2];
    const float* bq = (const float*)d_in[3];
    const float* Wk = (const float*)d_in[4];
    const float* bk = (const float*)d_in[5];
    const float* Wv = (const float*)d_in[6];
    const float* bv = (const float*)d_in[7];
    const float* Wo = (const float*)d_in[8];
    const float* bo = (const float*)d_in[9];

    char* ws = (char*)d_ws;
    const size_t MB = 1024 * 1024;
    float* Q     = (float*)(ws);                   //   8 MB [H][S][D]
    float* K     = (float*)(ws + 8 * MB);          //   8 MB
    float* V     = (float*)(ws + 16 * MB);         //   8 MB
    u16*   Sc    = (u16*)  (ws + 24 * MB);         // 128 MB [H][S][S] bf16
    u16*   hvy   = (u16*)  (ws + 152 * MB);        // ~10.2 MB [H][NSCAN][HB]
    float* rsumG = (float*)(ws + 163 * MB);        // 105 KB [H][NSCAN]
    float* accG  = (float*)(ws + 164 * MB);        //  26 KB [H][CB]
    float* O     = (float*)(ws + 168 * MB);        //   8 MB [S][E]
    (void)ws_size; (void)in_sizes; (void)n_in; (void)out_size;

    (void)hipMemsetAsync(accG, 0, (size_t)H_ * CB_ * sizeof(float), stream);
    qkv_gemm<<<dim3(8, 16, 3), 256, 0, stream>>>(hs, Wq, bq, Wk, bk, Wv, bv, Q, K, V);
    sc_gemm <<<dim3(32, 32, 16), 256, 0, stream>>>(Q, K, Sc);
    prep_kernel<<<dim3(NSCAN_ / 4 + CB_ / 4, H_), 256, 0, stream>>>(Sc, rsumG, accG);
    scan_fill<<<16 + NFULL_ + NPART_, 256, 0, stream>>>(Sc, accG, rsumG, hvy, V, O);
    heavy_merge<<<NPART_, 256, 0, stream>>>(Sc, V, hvy, rsumG, O);
    proj_gemm<<<dim3(8, 16, 1), 256, 0, stream>>>(O, Wo, bo, (float*)d_out);
}